// Round 1
// 474.623 us; speedup vs baseline: 1.1021x; 1.1021x over previous
//
#include <hip/hip_runtime.h>

// Problem constants (from reference)
#define C_IMG 16
#define GRIDSZ 128
#define VOL (GRIDSZ * GRIDSZ * GRIDSZ)
#define SLOPE 0.3f
#define SCALE 0.1f
#define EPB 4096         // edges per k_bucket block
#define HEPB 16384       // edges per k_hist block
#define BIN_CAP 16384    // max edges per 512-vertex bucket (mean 8192, sd ~90)

using f4_t  = __attribute__((ext_vector_type(4))) float;
using bf8_t = __attribute__((ext_vector_type(8))) short;

// bf16 helpers (manual, RNE pack / shift unpack)
__device__ __forceinline__ unsigned int bf16_pack2(float a, float b) {
    unsigned int ua = __float_as_uint(a);
    ua = (ua + 0x7FFFu + ((ua >> 16) & 1u)) >> 16;
    unsigned int ub = __float_as_uint(b);
    ub = (ub + 0x7FFFu + ((ub >> 16) & 1u)) >> 16;
    return ua | (ub << 16);
}
__device__ __forceinline__ unsigned short bf16_1(float a) {
    unsigned int ua = __float_as_uint(a);
    return (unsigned short)((ua + 0x7FFFu + ((ua >> 16) & 1u)) >> 16);
}
__device__ __forceinline__ float bf_lo(unsigned int u) { return __uint_as_float(u << 16); }
__device__ __forceinline__ float bf_hi(unsigned int u) { return __uint_as_float(u & 0xFFFF0000u); }

// ---------------------------------------------------------------------------
// Per-block LDS histogram of dst buckets (dst>>9), flushed with one global
// atomic per (block, bucket).
__global__ __launch_bounds__(256) void k_hist(const int* __restrict__ edst,
                                              int* __restrict__ bucketCount, int ne) {
    __shared__ int h[256];
    const int tid = threadIdx.x;
    h[tid] = 0;
    __syncthreads();
    const int base = blockIdx.x * HEPB;
    const int n = min(HEPB, ne - base);
    for (int i = tid; i < n; i += 256)
        atomicAdd(&h[((unsigned)edst[base + i]) >> 9], 1);
    __syncthreads();
    if (h[tid]) atomicAdd(&bucketCount[tid], h[tid]);
}

// Exclusive scan of <=256 bucket counts -> bucketBase (+ cursors); also sets
// bucketBase[np] = ne and rowStart[nv] = ne.
__global__ __launch_bounds__(256) void k_scan256(const int* __restrict__ bucketCount,
                                                 int* __restrict__ bucketBase,
                                                 int* __restrict__ bucketCursor,
                                                 int* __restrict__ rowStart,
                                                 int np, int nv, int ne) {
    __shared__ int buf[256];
    const int tid = threadIdx.x;
    const int v = (tid < np) ? bucketCount[tid] : 0;
    buf[tid] = v;
    __syncthreads();
    #pragma unroll
    for (int off = 1; off < 256; off <<= 1) {
        int t = (tid >= off) ? buf[tid - off] : 0;
        __syncthreads();
        buf[tid] += t;
        __syncthreads();
    }
    const int excl = buf[tid] - v;
    bucketBase[tid] = excl;
    bucketCursor[tid] = excl;
    if (tid == 0) {
        bucketBase[np] = ne;
        rowStart[nv] = ne;
    }
}

// Bucketing pass: group edges by dst>>9 into per-bucket global regions with
// dense (coalesced-run) writes. Packed pair: (src<<9)|(dst&511) — src<2^17.
// Bucket id for the flush kept in a parallel byte array.
__global__ __launch_bounds__(256) void k_bucket(const int* __restrict__ esrc,
                                                const int* __restrict__ edst,
                                                int* __restrict__ bucketCursor,
                                                unsigned int* __restrict__ pairs, int ne) {
    __shared__ unsigned int hist[256];
    __shared__ unsigned int pref[256];
    __shared__ unsigned int curs[256];
    __shared__ unsigned int gbase[256];
    __shared__ unsigned int stage_v[EPB];
    __shared__ unsigned char stage_b[EPB];
    const int tid = threadIdx.x;
    const int base = blockIdx.x * EPB;
    const int n = min(EPB, ne - base);
    hist[tid] = 0;
    __syncthreads();
    for (int i = tid; i < n; i += 256)
        atomicAdd(&hist[((unsigned)edst[base + i]) >> 9], 1u);
    __syncthreads();
    const unsigned int h = hist[tid];
    pref[tid] = h;
    __syncthreads();
    #pragma unroll
    for (int off = 1; off < 256; off <<= 1) {
        unsigned int t = (tid >= off) ? pref[tid - off] : 0;
        __syncthreads();
        pref[tid] += t;
        __syncthreads();
    }
    const unsigned int excl = pref[tid] - h;
    gbase[tid] = h ? (unsigned int)atomicAdd(&bucketCursor[tid], (int)h) : 0u;
    __syncthreads();
    pref[tid] = excl;
    curs[tid] = excl;
    __syncthreads();
    for (int i = tid; i < n; i += 256) {
        unsigned int d = (unsigned)edst[base + i];
        unsigned int s = (unsigned)esrc[base + i];
        unsigned int p = atomicAdd(&curs[d >> 9], 1u);
        stage_v[p] = (s << 9) | (d & 511u);
        stage_b[p] = (unsigned char)(d >> 9);
    }
    __syncthreads();
    for (int i = tid; i < n; i += 256) {
        unsigned int b = stage_b[i];
        pairs[gbase[b] + (unsigned)i - pref[b]] = stage_v[i];
    }
}

// Within-bucket: per-vertex degree + rowStart + invdeg in LDS, then scatter
// srcs via LDS cursors, flush coalesced. One block per 512-vtx bucket.
__global__ __launch_bounds__(256) void k_binsort(const unsigned int* __restrict__ pairs,
                                                 const int* __restrict__ bucketBase,
                                                 int* __restrict__ rowStart,
                                                 float* __restrict__ invdeg,
                                                 int* __restrict__ csrSrc, int nv) {
    __shared__ int deg_s[512];
    __shared__ int rs_s[512];
    __shared__ int cur_s[512];
    __shared__ int scan_s[256];
    __shared__ int outbuf[BIN_CAP];
    const int tid = threadIdx.x;
    const int b = blockIdx.x;
    const int vbase = b << 9;
    if (vbase >= nv) return;
    const int nvb = min(512, nv - vbase);
    const int gs = bucketBase[b];
    const int ge = bucketBase[b + 1];
    const int count = ge - gs;
    deg_s[tid] = 0;
    deg_s[tid + 256] = 0;
    __syncthreads();
    // pass 1: degrees
    for (int i = tid; i < count; i += 256) {
        unsigned int p = pairs[gs + i];
        atomicAdd(&deg_s[p & 511u], 1);
    }
    __syncthreads();
    // scan 512 degrees (2 per thread)
    const int d0 = deg_s[2 * tid];
    const int d1 = deg_s[2 * tid + 1];
    const int ps = d0 + d1;
    scan_s[tid] = ps;
    __syncthreads();
    #pragma unroll
    for (int off = 1; off < 256; off <<= 1) {
        int t = (tid >= off) ? scan_s[tid - off] : 0;
        __syncthreads();
        scan_s[tid] += t;
        __syncthreads();
    }
    const int epair = scan_s[tid] - ps;
    rs_s[2 * tid] = epair;
    rs_s[2 * tid + 1] = epair + d0;
    cur_s[2 * tid] = epair;
    cur_s[2 * tid + 1] = epair + d0;
    #pragma unroll
    for (int u = 0; u < 2; ++u) {
        int idx = 2 * tid + u;
        if (idx < nvb) {
            rowStart[vbase + idx] = gs + rs_s[idx];
            int d = deg_s[idx];
            invdeg[vbase + idx] = 1.0f / (float)(d > 1 ? d : 1);
        }
    }
    __syncthreads();
    // pass 2: scatter
    if (count <= BIN_CAP) {
        for (int i = tid; i < count; i += 256) {
            unsigned int p = pairs[gs + i];
            int pos = atomicAdd(&cur_s[p & 511u], 1);
            outbuf[pos] = (int)(p >> 9);
        }
        __syncthreads();
        for (int i = tid; i < count; i += 256) csrSrc[gs + i] = outbuf[i];
    } else {
        // statistically unreachable; uncoalesced but correct
        for (int i = tid; i < count; i += 256) {
            unsigned int p = pairs[gs + i];
            int pos = atomicAdd(&cur_s[p & 511u], 1);
            csrSrc[gs + pos] = (int)(p >> 9);
        }
    }
}

// ---------------------------------------------------------------------------
// Image transpose: img[16][128][128][128] fp32 -> timg[x][y][z][16] bf16.
__global__ __launch_bounds__(256) void k_transpose(const float* __restrict__ img,
                                                   unsigned int* __restrict__ timg) {
    const int t = blockIdx.x * 256 + threadIdx.x;
    const int q  = t & 3;
    const int z4 = (t >> 2) & 31;
    const int xy = t >> 7;
    const int z0 = z4 * 4;
    const int c0 = q * 4;
    const size_t base = (size_t)xy * GRIDSZ + z0;
    float4 v0 = *(const float4*)(img + (size_t)(c0 + 0) * VOL + base);
    float4 v1 = *(const float4*)(img + (size_t)(c0 + 1) * VOL + base);
    float4 v2 = *(const float4*)(img + (size_t)(c0 + 2) * VOL + base);
    float4 v3 = *(const float4*)(img + (size_t)(c0 + 3) * VOL + base);
    #pragma unroll
    for (int j = 0; j < 4; ++j) {
        float f0 = (j == 0) ? v0.x : (j == 1) ? v0.y : (j == 2) ? v0.z : v0.w;
        float f1 = (j == 0) ? v1.x : (j == 1) ? v1.y : (j == 2) ? v1.z : v1.w;
        float f2 = (j == 0) ? v2.x : (j == 1) ? v2.y : (j == 2) ? v2.z : v2.w;
        float f3 = (j == 0) ? v3.x : (j == 1) ? v3.y : (j == 2) ? v3.z : v3.w;
        uint2 o;
        o.x = bf16_pack2(f0, f1);
        o.y = bf16_pack2(f2, f3);
        *(uint2*)(timg + (size_t)(xy * GRIDSZ + z0 + j) * 8 + q * 2) = o;
    }
}

// ---------------------------------------------------------------------------
// Trilinear sample -> bf16 feats rows, stride 16 uints (32 bf16 cols):
// cols 0..15 = channels, 16..18 = verts/128, 19..31 = 0.
__global__ __launch_bounds__(256) void k_sample(const unsigned int* __restrict__ timg,
                                                const float* __restrict__ verts,
                                                unsigned int* __restrict__ feats, int nv) {
    int t = blockIdx.x * 256 + threadIdx.x;
    int v = t >> 1;
    int q = t & 1;          // channel group: q*8 .. q*8+7
    if (v >= nv) return;
    float px = verts[v * 3 + 0];
    float py = verts[v * 3 + 1];
    float pz = verts[v * 3 + 2];
    float cx = fminf(fmaxf(px, 0.0f), 127.0f);
    float cy = fminf(fmaxf(py, 0.0f), 127.0f);
    float cz = fminf(fmaxf(pz, 0.0f), 127.0f);
    float fx = floorf(cx), fy = floorf(cy), fz = floorf(cz);
    int x0 = (int)fx, y0 = (int)fy, z0 = (int)fz;
    int x1 = min(x0 + 1, 127), y1 = min(y0 + 1, 127), z1 = min(z0 + 1, 127);
    float wx = cx - fx, wy = cy - fy, wz = cz - fz;
    const int qo = q * 4;
    #define LD(X, Y, Z) (*(const uint4*)(timg + ((size_t)((((X) << 7) + (Y)) << 7) + (size_t)(Z)) * 8 + qo))
    uint4 f000 = LD(x0, y0, z0), f001 = LD(x0, y0, z1);
    uint4 f010 = LD(x0, y1, z0), f011 = LD(x0, y1, z1);
    uint4 f100 = LD(x1, y0, z0), f101 = LD(x1, y0, z1);
    uint4 f110 = LD(x1, y1, z0), f111 = LD(x1, y1, z1);
    #undef LD
    float r[8];
    const unsigned int* a000 = (const unsigned int*)&f000;
    const unsigned int* a001 = (const unsigned int*)&f001;
    const unsigned int* a010 = (const unsigned int*)&f010;
    const unsigned int* a011 = (const unsigned int*)&f011;
    const unsigned int* a100 = (const unsigned int*)&f100;
    const unsigned int* a101 = (const unsigned int*)&f101;
    const unsigned int* a110 = (const unsigned int*)&f110;
    const unsigned int* a111 = (const unsigned int*)&f111;
    #pragma unroll
    for (int u = 0; u < 4; ++u) {
        float c00l = bf_lo(a000[u]) * (1.f - wz) + bf_lo(a001[u]) * wz;
        float c01l = bf_lo(a010[u]) * (1.f - wz) + bf_lo(a011[u]) * wz;
        float c10l = bf_lo(a100[u]) * (1.f - wz) + bf_lo(a101[u]) * wz;
        float c11l = bf_lo(a110[u]) * (1.f - wz) + bf_lo(a111[u]) * wz;
        r[2 * u] = (c00l * (1.f - wy) + c01l * wy) * (1.f - wx) +
                   (c10l * (1.f - wy) + c11l * wy) * wx;
        float c00h = bf_hi(a000[u]) * (1.f - wz) + bf_hi(a001[u]) * wz;
        float c01h = bf_hi(a010[u]) * (1.f - wz) + bf_hi(a011[u]) * wz;
        float c10h = bf_hi(a100[u]) * (1.f - wz) + bf_hi(a101[u]) * wz;
        float c11h = bf_hi(a110[u]) * (1.f - wz) + bf_hi(a111[u]) * wz;
        r[2 * u + 1] = (c00h * (1.f - wy) + c01h * wy) * (1.f - wx) +
                       (c10h * (1.f - wy) + c11h * wy) * wx;
    }
    unsigned int* row = feats + (size_t)v * 16;
    uint4 o;
    o.x = bf16_pack2(r[0], r[1]); o.y = bf16_pack2(r[2], r[3]);
    o.z = bf16_pack2(r[4], r[5]); o.w = bf16_pack2(r[6], r[7]);
    *(uint4*)(row + q * 4) = o;
    if (q == 0) {
        uint4 o2;
        o2.x = bf16_pack2(px * (1.0f / 128.0f), py * (1.0f / 128.0f));
        o2.y = bf16_pack2(pz * (1.0f / 128.0f), 0.0f);
        o2.z = 0u; o2.w = 0u;
        *(uint4*)(row + 8) = o2;
        *(uint4*)(row + 12) = make_uint4(0u, 0u, 0u, 0u);
    }
}

// ---------------------------------------------------------------------------
// CSR gather-sum over bf16 rows (stride SU uints). NCH=SU/4 threads per
// vertex, each owns a uint4 (8 ch) chunk; fp32 accumulate, scaled by
// invdeg[v] (folded here so the layer GEMM is a single concat-K matmul),
// bf16 output. 2x unrolled edge loop for load ILP.
template <int SU>
__global__ __launch_bounds__(256) void k_gather16(const unsigned int* __restrict__ x,
                                                  const int* __restrict__ rowStart,
                                                  const int* __restrict__ csrSrc,
                                                  const float* __restrict__ invdeg,
                                                  unsigned int* __restrict__ nb, int nv) {
    constexpr int NCH = SU / 4;
    int t = blockIdx.x * 256 + threadIdx.x;
    int v = t / NCH;
    if (v >= nv) return;
    int ch = t - v * NCH;
    int beg = rowStart[v];
    int end = rowStart[v + 1];
    float a0 = 0.f, a1 = 0.f, a2 = 0.f, a3 = 0.f, a4 = 0.f, a5 = 0.f, a6 = 0.f, a7 = 0.f;
    int j = beg;
    for (; j + 1 < end; j += 2) {
        int s0 = csrSrc[j];
        int s1 = csrSrc[j + 1];
        uint4 q0 = ((const uint4*)(x + (size_t)s0 * SU))[ch];
        uint4 q1 = ((const uint4*)(x + (size_t)s1 * SU))[ch];
        a0 += bf_lo(q0.x); a1 += bf_hi(q0.x);
        a2 += bf_lo(q0.y); a3 += bf_hi(q0.y);
        a4 += bf_lo(q0.z); a5 += bf_hi(q0.z);
        a6 += bf_lo(q0.w); a7 += bf_hi(q0.w);
        a0 += bf_lo(q1.x); a1 += bf_hi(q1.x);
        a2 += bf_lo(q1.y); a3 += bf_hi(q1.y);
        a4 += bf_lo(q1.z); a5 += bf_hi(q1.z);
        a6 += bf_lo(q1.w); a7 += bf_hi(q1.w);
    }
    if (j < end) {
        int s = csrSrc[j];
        uint4 q = ((const uint4*)(x + (size_t)s * SU))[ch];
        a0 += bf_lo(q.x); a1 += bf_hi(q.x);
        a2 += bf_lo(q.y); a3 += bf_hi(q.y);
        a4 += bf_lo(q.z); a5 += bf_hi(q.z);
        a6 += bf_lo(q.w); a7 += bf_hi(q.w);
    }
    const float id = invdeg[v];
    uint4 o;
    o.x = bf16_pack2(a0 * id, a1 * id); o.y = bf16_pack2(a2 * id, a3 * id);
    o.z = bf16_pack2(a4 * id, a5 * id); o.w = bf16_pack2(a6 * id, a7 * id);
    ((uint4*)(nb + (size_t)v * SU))[ch] = o;
}

// ---------------------------------------------------------------------------
// MFMA edge-conv dense part: out = leakyrelu([x | nb_scaled] @ [[Ws],[Wn]] + b).
// KX = padded x-row width (SXU*2 bf16 cols), concat K = 2*KX. Weights built
// as bf16 N-major (Bt[c][kk]) in LDS with +8 element pad (bank-rotate).
// A frag: lane row = l&15, 8 contiguous k at (l>>4)*8 -> one 16B global load.
// B frag: lane col = l&15, same k slice -> one 16B LDS read.
// D: col = lane&15, row = (lane>>4)*4 + reg  [m89-verified mapping].
template <int KX, int COUT, bool REMAP0, int VALID_CIN>
__global__ __launch_bounds__(256) void k_layer_mfma(const unsigned int* __restrict__ x,
                                                    const unsigned int* __restrict__ nbs,
                                                    const float* __restrict__ Ws,
                                                    const float* __restrict__ Wn,
                                                    const float* __restrict__ bias,
                                                    unsigned int* __restrict__ out, int nv) {
    constexpr int KTOT = 2 * KX;
    constexpr int KW = KTOT + 8;      // LDS row stride (bf16 elems), bank-rotating
    constexpr int NT = COUT / 16;     // n-tiles per wave
    constexpr int MT = 2;             // m-tiles per wave (32 vertices)
    constexpr int SXU = KX / 2;       // input row stride in uints
    constexpr int KS = KX / 32;       // k-steps per source
    __shared__ __align__(16) unsigned short bt[COUT * KW];

    // Build transposed bf16 weight block: bt[c][kk], kk<KX -> Ws, else Wn.
    for (int i = threadIdx.x; i < COUT * KTOT; i += 256) {
        int c = i / KTOT;
        int kk = i - c * KTOT;
        int j = (kk < KX) ? kk : kk - KX;
        const float* W = (kk < KX) ? Ws : Wn;
        float w = 0.f;
        if (j < VALID_CIN) {
            int sr = REMAP0 ? ((j < 16) ? (j + 3) : (j - 16)) : j;
            w = W[sr * COUT + c];
        }
        bt[c * KW + kk] = bf16_1(w);
    }
    __syncthreads();

    const int lane = threadIdx.x & 63;
    const int wid = threadIdx.x >> 6;
    const int v0 = blockIdx.x * (4 * MT * 16) + wid * (MT * 16);
    const int row = lane & 15;
    const int kg = lane >> 4;         // k-subgroup: 8 contiguous k at kg*8

    f4_t acc[MT][NT] = {};

    #pragma unroll
    for (int ks = 0; ks < 2 * KS; ++ks) {
        const unsigned int* src = (ks < KS) ? x : nbs;
        const int kbase = (ks < KS) ? ks * 32 : (ks - KS) * 32;
        bf8_t afrag[MT];
        #pragma unroll
        for (int mt = 0; mt < MT; ++mt) {
            int v = v0 + mt * 16 + row;
            v = min(v, nv - 1);       // clamp: duplicate row, results masked at store
            afrag[mt] = *(const bf8_t*)(src + (size_t)v * SXU + ((kbase + kg * 8) >> 1));
        }
        #pragma unroll
        for (int nt = 0; nt < NT; ++nt) {
            bf8_t bfrag = *(const bf8_t*)(bt + (nt * 16 + row) * KW + ks * 32 + kg * 8);
            #pragma unroll
            for (int mt = 0; mt < MT; ++mt)
                acc[mt][nt] = __builtin_amdgcn_mfma_f32_16x16x32_bf16(afrag[mt], bfrag,
                                                                      acc[mt][nt], 0, 0, 0);
        }
    }

    // Epilogue: bias + leaky relu, bf16 2B stores (16-lane groups are 32B runs).
    unsigned short* po = (unsigned short*)out;
    #pragma unroll
    for (int nt = 0; nt < NT; ++nt) {
        const int co = nt * 16 + row;
        const float bv = bias[co];
        #pragma unroll
        for (int mt = 0; mt < MT; ++mt) {
            const int vst = v0 + mt * 16 + kg * 4;
            #pragma unroll
            for (int r = 0; r < 4; ++r) {
                int v = vst + r;
                if (v < nv) {
                    float t = acc[mt][nt][r] + bv;
                    t = (t >= 0.f) ? t : SLOPE * t;
                    po[(size_t)v * COUT + co] = bf16_1(t);
                }
            }
        }
    }
}

// Pre-multiply for layer 3: z[v] = h3[v] @ Wn3 (3 cols), bf16 in/out.
__global__ __launch_bounds__(256) void k_premul(const unsigned int* __restrict__ h,
                                                const float* __restrict__ wn,
                                                unsigned int* __restrict__ z, int nv) {
    __shared__ float w_s[64 * 3];
    if (threadIdx.x < 64 * 3) w_s[threadIdx.x] = wn[threadIdx.x];
    __syncthreads();
    int v = blockIdx.x * 256 + threadIdx.x;
    if (v >= nv) return;
    const uint4* hr = (const uint4*)(h + (size_t)v * 32);
    float a0 = 0.f, a1 = 0.f, a2 = 0.f;
    #pragma unroll
    for (int q = 0; q < 8; ++q) {
        uint4 hv = hr[q];
        float f[8] = {bf_lo(hv.x), bf_hi(hv.x), bf_lo(hv.y), bf_hi(hv.y),
                      bf_lo(hv.z), bf_hi(hv.z), bf_lo(hv.w), bf_hi(hv.w)};
        #pragma unroll
        for (int i = 0; i < 8; ++i) {
            int k = q * 8 + i;
            a0 += f[i] * w_s[k * 3 + 0];
            a1 += f[i] * w_s[k * 3 + 1];
            a2 += f[i] * w_s[k * 3 + 2];
        }
    }
    uint2 o;
    o.x = bf16_pack2(a0, a1);
    o.y = bf16_pack2(a2, 0.f);
    *(uint2*)(z + (size_t)v * 2) = o;
}

// Final (fused z-gather): out = verts + SCALE*(h3@Ws3 + gather(z)*inv_deg + b3)
__global__ __launch_bounds__(256) void k_final(const unsigned int* __restrict__ h,
                                               const unsigned int* __restrict__ z,
                                               const int* __restrict__ rowStart,
                                               const int* __restrict__ csrSrc,
                                               const float* __restrict__ invdeg,
                                               const float* __restrict__ ws,
                                               const float* __restrict__ b,
                                               const float* __restrict__ verts,
                                               float* __restrict__ out, int nv) {
    __shared__ float w_s[64 * 3];
    if (threadIdx.x < 64 * 3) w_s[threadIdx.x] = ws[threadIdx.x];
    __syncthreads();
    int v = blockIdx.x * 256 + threadIdx.x;
    if (v >= nv) return;
    float n0 = 0.f, n1 = 0.f, n2 = 0.f;
    {
        int beg = rowStart[v];
        int end = rowStart[v + 1];
        for (int j = beg; j < end; ++j) {
            int s = csrSrc[j];
            uint2 q = *(const uint2*)(z + (size_t)s * 2);
            n0 += bf_lo(q.x); n1 += bf_hi(q.x); n2 += bf_lo(q.y);
        }
    }
    const uint4* hr = (const uint4*)(h + (size_t)v * 32);
    float a0 = b[0], a1 = b[1], a2 = b[2];
    #pragma unroll
    for (int q = 0; q < 8; ++q) {
        uint4 hv = hr[q];
        float f[8] = {bf_lo(hv.x), bf_hi(hv.x), bf_lo(hv.y), bf_hi(hv.y),
                      bf_lo(hv.z), bf_hi(hv.z), bf_lo(hv.w), bf_hi(hv.w)};
        #pragma unroll
        for (int i = 0; i < 8; ++i) {
            int k = q * 8 + i;
            a0 += f[i] * w_s[k * 3 + 0];
            a1 += f[i] * w_s[k * 3 + 1];
            a2 += f[i] * w_s[k * 3 + 2];
        }
    }
    float id = invdeg[v];
    a0 += n0 * id; a1 += n1 * id; a2 += n2 * id;
    out[(size_t)v * 3 + 0] = verts[(size_t)v * 3 + 0] + SCALE * a0;
    out[(size_t)v * 3 + 1] = verts[(size_t)v * 3 + 1] + SCALE * a1;
    out[(size_t)v * 3 + 2] = verts[(size_t)v * 3 + 2] + SCALE * a2;
}

// ---------------------------------------------------------------------------
extern "C" void kernel_launch(void* const* d_in, const int* in_sizes, int n_in,
                              void* d_out, int out_size, void* d_ws, size_t ws_size,
                              hipStream_t stream) {
    const float* img   = (const float*)d_in[0];
    const float* verts = (const float*)d_in[1];
    const int*   esrc  = (const int*)d_in[2];
    const int*   edst  = (const int*)d_in[3];
    const float* ws0 = (const float*)d_in[4];
    const float* wn0 = (const float*)d_in[5];
    const float* b0  = (const float*)d_in[6];
    const float* ws1 = (const float*)d_in[7];
    const float* wn1 = (const float*)d_in[8];
    const float* b1  = (const float*)d_in[9];
    const float* ws2 = (const float*)d_in[10];
    const float* wn2 = (const float*)d_in[11];
    const float* b2  = (const float*)d_in[12];
    const float* ws3 = (const float*)d_in[13];
    const float* wn3 = (const float*)d_in[14];
    const float* b3  = (const float*)d_in[15];

    const int nv = in_sizes[1] / 3;
    const int ne = in_sizes[2];

    char* base = (char*)d_ws;
    size_t off = 0;
    auto alloc = [&](size_t bytes) -> void* {
        off = (off + 255) & ~(size_t)255;
        void* p = base + off;
        off += bytes;
        return p;
    };
    float* invdeg   = (float*)alloc((size_t)nv * 4);
    int*   rowStart = (int*)alloc((size_t)(nv + 1) * 4);
    int*   bucketCount  = (int*)alloc(256 * 4);
    int*   bucketBase   = (int*)alloc(257 * 4);
    int*   bucketCursor = (int*)alloc(256 * 4);
    int*   csrSrc   = (int*)alloc((size_t)ne * 4);
    unsigned int* A   = (unsigned int*)alloc((size_t)nv * 32 * 4);  // feats(16u) then h2(32u)
    unsigned int* B   = (unsigned int*)alloc((size_t)nv * 32 * 4);  // h1(16u) then h3(32u)
    unsigned int* NBu = (unsigned int*)alloc((size_t)nv * 32 * 4);  // bf16 neighbor sums
    unsigned int* Z   = (unsigned int*)alloc((size_t)nv * 2 * 4);   // bf16 premultiplied
    unsigned int* timg = (unsigned int*)alloc((size_t)VOL * 16 * 2);
    unsigned int* pairs = (unsigned int*)NBu;  // alias: ne*4 <= nv*32*4 bytes

    auto blocks = [](long long n) { return (int)((n + 255) / 256); };
    const int nbuckets = (nv + 511) >> 9;
    const int lb = (nv + 127) / 128;  // k_layer_mfma: 128 vertices per block

    // Image transpose (independent of CSR build)
    k_transpose<<<(GRIDSZ * GRIDSZ * 32 * 4) / 256, 256, 0, stream>>>(img, timg);

    // CSR build: bucket histogram -> scan -> bucketing -> per-bucket sort
    hipMemsetAsync(bucketCount, 0, 256 * 4, stream);
    k_hist<<<(ne + HEPB - 1) / HEPB, 256, 0, stream>>>(edst, bucketCount, ne);
    k_scan256<<<1, 256, 0, stream>>>(bucketCount, bucketBase, bucketCursor, rowStart, nbuckets, nv, ne);
    k_bucket<<<(ne + EPB - 1) / EPB, 256, 0, stream>>>(esrc, edst, bucketCursor, pairs, ne);
    k_binsort<<<nbuckets, 256, 0, stream>>>(pairs, bucketBase, rowStart, invdeg, csrSrc, nv);

    // Features (channel-last bf16 volume) -> bf16 feats
    k_sample<<<blocks((long long)nv * 2), 256, 0, stream>>>(timg, verts, A, nv);

    // Layer 0: 19 -> 32 (feats stride 16u, KX=32)
    k_gather16<16><<<blocks((long long)nv * 4), 256, 0, stream>>>(A, rowStart, csrSrc, invdeg, NBu, nv);
    k_layer_mfma<32, 32, true, 19><<<lb, 256, 0, stream>>>(A, NBu, ws0, wn0, b0, B, nv);

    // Layer 1: 32 -> 64 (h1 stride 16u, KX=32)
    k_gather16<16><<<blocks((long long)nv * 4), 256, 0, stream>>>(B, rowStart, csrSrc, invdeg, NBu, nv);
    k_layer_mfma<32, 64, false, 32><<<lb, 256, 0, stream>>>(B, NBu, ws1, wn1, b1, A, nv);

    // Layer 2: 64 -> 64 (h2 stride 32u, KX=64)
    k_gather16<32><<<blocks((long long)nv * 8), 256, 0, stream>>>(A, rowStart, csrSrc, invdeg, NBu, nv);
    k_layer_mfma<64, 64, false, 64><<<lb, 256, 0, stream>>>(A, NBu, ws2, wn2, b2, B, nv);

    // Layer 3: pre-multiply by Wn3 (64->3), fused gather+final update
    k_premul<<<blocks(nv), 256, 0, stream>>>(B, wn3, Z, nv);
    k_final<<<blocks(nv), 256, 0, stream>>>(
        B, Z, rowStart, csrSrc, invdeg, ws3, b3, verts, (float*)d_out, nv);
}

// Round 2
// 459.560 us; speedup vs baseline: 1.1383x; 1.0328x over previous
//
#include <hip/hip_runtime.h>

// Problem constants (from reference)
#define C_IMG 16
#define GRIDSZ 128
#define VOL (GRIDSZ * GRIDSZ * GRIDSZ)
#define SLOPE 0.3f
#define SCALE 0.1f
#define EPB 4096         // edges per k_bucket block
#define HEPB 16384       // edges per k_hist block
#define BIN_CAP 16384    // max edges per 512-vertex bucket (mean 8192, sd ~90)

using f4_t  = __attribute__((ext_vector_type(4))) float;
using bf8_t = __attribute__((ext_vector_type(8))) short;

// bf16 helpers (manual, RNE pack / shift unpack)
__device__ __forceinline__ unsigned int bf16_pack2(float a, float b) {
    unsigned int ua = __float_as_uint(a);
    ua = (ua + 0x7FFFu + ((ua >> 16) & 1u)) >> 16;
    unsigned int ub = __float_as_uint(b);
    ub = (ub + 0x7FFFu + ((ub >> 16) & 1u)) >> 16;
    return ua | (ub << 16);
}
__device__ __forceinline__ unsigned short bf16_1(float a) {
    unsigned int ua = __float_as_uint(a);
    return (unsigned short)((ua + 0x7FFFu + ((ua >> 16) & 1u)) >> 16);
}
__device__ __forceinline__ float bf_lo(unsigned int u) { return __uint_as_float(u << 16); }
__device__ __forceinline__ float bf_hi(unsigned int u) { return __uint_as_float(u & 0xFFFF0000u); }

// ---------------------------------------------------------------------------
// Per-block LDS histogram of dst buckets (dst>>9), flushed with one global
// atomic per (block, bucket).
__global__ __launch_bounds__(256) void k_hist(const int* __restrict__ edst,
                                              int* __restrict__ bucketCount, int ne) {
    __shared__ int h[256];
    const int tid = threadIdx.x;
    h[tid] = 0;
    __syncthreads();
    const int base = blockIdx.x * HEPB;
    const int n = min(HEPB, ne - base);
    for (int i = tid; i < n; i += 256)
        atomicAdd(&h[((unsigned)edst[base + i]) >> 9], 1);
    __syncthreads();
    if (h[tid]) atomicAdd(&bucketCount[tid], h[tid]);
}

// Exclusive scan of <=256 bucket counts -> bucketBase (+ cursors); also sets
// bucketBase[np] = ne and rowStart[nv] = ne.
__global__ __launch_bounds__(256) void k_scan256(const int* __restrict__ bucketCount,
                                                 int* __restrict__ bucketBase,
                                                 int* __restrict__ bucketCursor,
                                                 int* __restrict__ rowStart,
                                                 int np, int nv, int ne) {
    __shared__ int buf[256];
    const int tid = threadIdx.x;
    const int v = (tid < np) ? bucketCount[tid] : 0;
    buf[tid] = v;
    __syncthreads();
    #pragma unroll
    for (int off = 1; off < 256; off <<= 1) {
        int t = (tid >= off) ? buf[tid - off] : 0;
        __syncthreads();
        buf[tid] += t;
        __syncthreads();
    }
    const int excl = buf[tid] - v;
    bucketBase[tid] = excl;
    bucketCursor[tid] = excl;
    if (tid == 0) {
        bucketBase[np] = ne;
        rowStart[nv] = ne;
    }
}

// Bucketing pass: group edges by dst>>9 into per-bucket global regions with
// dense (coalesced-run) writes. Packed pair: (src<<9)|(dst&511) — src<2^17.
__global__ __launch_bounds__(256) void k_bucket(const int* __restrict__ esrc,
                                                const int* __restrict__ edst,
                                                int* __restrict__ bucketCursor,
                                                unsigned int* __restrict__ pairs, int ne) {
    __shared__ unsigned int hist[256];
    __shared__ unsigned int pref[256];
    __shared__ unsigned int curs[256];
    __shared__ unsigned int gbase[256];
    __shared__ unsigned int stage_v[EPB];
    __shared__ unsigned char stage_b[EPB];
    const int tid = threadIdx.x;
    const int base = blockIdx.x * EPB;
    const int n = min(EPB, ne - base);
    hist[tid] = 0;
    __syncthreads();
    for (int i = tid; i < n; i += 256)
        atomicAdd(&hist[((unsigned)edst[base + i]) >> 9], 1u);
    __syncthreads();
    const unsigned int h = hist[tid];
    pref[tid] = h;
    __syncthreads();
    #pragma unroll
    for (int off = 1; off < 256; off <<= 1) {
        unsigned int t = (tid >= off) ? pref[tid - off] : 0;
        __syncthreads();
        pref[tid] += t;
        __syncthreads();
    }
    const unsigned int excl = pref[tid] - h;
    gbase[tid] = h ? (unsigned int)atomicAdd(&bucketCursor[tid], (int)h) : 0u;
    __syncthreads();
    pref[tid] = excl;
    curs[tid] = excl;
    __syncthreads();
    for (int i = tid; i < n; i += 256) {
        unsigned int d = (unsigned)edst[base + i];
        unsigned int s = (unsigned)esrc[base + i];
        unsigned int p = atomicAdd(&curs[d >> 9], 1u);
        stage_v[p] = (s << 9) | (d & 511u);
        stage_b[p] = (unsigned char)(d >> 9);
    }
    __syncthreads();
    for (int i = tid; i < n; i += 256) {
        unsigned int b = stage_b[i];
        pairs[gbase[b] + (unsigned)i - pref[b]] = stage_v[i];
    }
}

// Within-bucket: per-vertex degree + rowStart + invdeg in LDS, then scatter
// srcs via LDS cursors, flush coalesced. One block per 512-vtx bucket.
__global__ __launch_bounds__(256) void k_binsort(const unsigned int* __restrict__ pairs,
                                                 const int* __restrict__ bucketBase,
                                                 int* __restrict__ rowStart,
                                                 float* __restrict__ invdeg,
                                                 int* __restrict__ csrSrc, int nv) {
    __shared__ int deg_s[512];
    __shared__ int rs_s[512];
    __shared__ int cur_s[512];
    __shared__ int scan_s[256];
    __shared__ int outbuf[BIN_CAP];
    const int tid = threadIdx.x;
    const int b = blockIdx.x;
    const int vbase = b << 9;
    if (vbase >= nv) return;
    const int nvb = min(512, nv - vbase);
    const int gs = bucketBase[b];
    const int ge = bucketBase[b + 1];
    const int count = ge - gs;
    deg_s[tid] = 0;
    deg_s[tid + 256] = 0;
    __syncthreads();
    // pass 1: degrees
    for (int i = tid; i < count; i += 256) {
        unsigned int p = pairs[gs + i];
        atomicAdd(&deg_s[p & 511u], 1);
    }
    __syncthreads();
    // scan 512 degrees (2 per thread)
    const int d0 = deg_s[2 * tid];
    const int d1 = deg_s[2 * tid + 1];
    const int ps = d0 + d1;
    scan_s[tid] = ps;
    __syncthreads();
    #pragma unroll
    for (int off = 1; off < 256; off <<= 1) {
        int t = (tid >= off) ? scan_s[tid - off] : 0;
        __syncthreads();
        scan_s[tid] += t;
        __syncthreads();
    }
    const int epair = scan_s[tid] - ps;
    rs_s[2 * tid] = epair;
    rs_s[2 * tid + 1] = epair + d0;
    cur_s[2 * tid] = epair;
    cur_s[2 * tid + 1] = epair + d0;
    #pragma unroll
    for (int u = 0; u < 2; ++u) {
        int idx = 2 * tid + u;
        if (idx < nvb) {
            rowStart[vbase + idx] = gs + rs_s[idx];
            int d = deg_s[idx];
            invdeg[vbase + idx] = 1.0f / (float)(d > 1 ? d : 1);
        }
    }
    __syncthreads();
    // pass 2: scatter
    if (count <= BIN_CAP) {
        for (int i = tid; i < count; i += 256) {
            unsigned int p = pairs[gs + i];
            int pos = atomicAdd(&cur_s[p & 511u], 1);
            outbuf[pos] = (int)(p >> 9);
        }
        __syncthreads();
        for (int i = tid; i < count; i += 256) csrSrc[gs + i] = outbuf[i];
    } else {
        // statistically unreachable; uncoalesced but correct
        for (int i = tid; i < count; i += 256) {
            unsigned int p = pairs[gs + i];
            int pos = atomicAdd(&cur_s[p & 511u], 1);
            csrSrc[gs + pos] = (int)(p >> 9);
        }
    }
}

// ---------------------------------------------------------------------------
// Image transpose: img[16][128][128][128] fp32 -> timg[x][y][z][16] bf16.
__global__ __launch_bounds__(256) void k_transpose(const float* __restrict__ img,
                                                   unsigned int* __restrict__ timg) {
    const int t = blockIdx.x * 256 + threadIdx.x;
    const int q  = t & 3;
    const int z4 = (t >> 2) & 31;
    const int xy = t >> 7;
    const int z0 = z4 * 4;
    const int c0 = q * 4;
    const size_t base = (size_t)xy * GRIDSZ + z0;
    float4 v0 = *(const float4*)(img + (size_t)(c0 + 0) * VOL + base);
    float4 v1 = *(const float4*)(img + (size_t)(c0 + 1) * VOL + base);
    float4 v2 = *(const float4*)(img + (size_t)(c0 + 2) * VOL + base);
    float4 v3 = *(const float4*)(img + (size_t)(c0 + 3) * VOL + base);
    #pragma unroll
    for (int j = 0; j < 4; ++j) {
        float f0 = (j == 0) ? v0.x : (j == 1) ? v0.y : (j == 2) ? v0.z : v0.w;
        float f1 = (j == 0) ? v1.x : (j == 1) ? v1.y : (j == 2) ? v1.z : v1.w;
        float f2 = (j == 0) ? v2.x : (j == 1) ? v2.y : (j == 2) ? v2.z : v2.w;
        float f3 = (j == 0) ? v3.x : (j == 1) ? v3.y : (j == 2) ? v3.z : v3.w;
        uint2 o;
        o.x = bf16_pack2(f0, f1);
        o.y = bf16_pack2(f2, f3);
        *(uint2*)(timg + (size_t)(xy * GRIDSZ + z0 + j) * 8 + q * 2) = o;
    }
}

// ---------------------------------------------------------------------------
// Trilinear sample -> bf16 feats rows, stride 16 uints (32 bf16 cols):
// cols 0..15 = channels, 16..18 = verts/128, 19..31 = 0.
__global__ __launch_bounds__(256) void k_sample(const unsigned int* __restrict__ timg,
                                                const float* __restrict__ verts,
                                                unsigned int* __restrict__ feats, int nv) {
    int t = blockIdx.x * 256 + threadIdx.x;
    int v = t >> 1;
    int q = t & 1;          // channel group: q*8 .. q*8+7
    if (v >= nv) return;
    float px = verts[v * 3 + 0];
    float py = verts[v * 3 + 1];
    float pz = verts[v * 3 + 2];
    float cx = fminf(fmaxf(px, 0.0f), 127.0f);
    float cy = fminf(fmaxf(py, 0.0f), 127.0f);
    float cz = fminf(fmaxf(pz, 0.0f), 127.0f);
    float fx = floorf(cx), fy = floorf(cy), fz = floorf(cz);
    int x0 = (int)fx, y0 = (int)fy, z0 = (int)fz;
    int x1 = min(x0 + 1, 127), y1 = min(y0 + 1, 127), z1 = min(z0 + 1, 127);
    float wx = cx - fx, wy = cy - fy, wz = cz - fz;
    const int qo = q * 4;
    #define LD(X, Y, Z) (*(const uint4*)(timg + ((size_t)((((X) << 7) + (Y)) << 7) + (size_t)(Z)) * 8 + qo))
    uint4 f000 = LD(x0, y0, z0), f001 = LD(x0, y0, z1);
    uint4 f010 = LD(x0, y1, z0), f011 = LD(x0, y1, z1);
    uint4 f100 = LD(x1, y0, z0), f101 = LD(x1, y0, z1);
    uint4 f110 = LD(x1, y1, z0), f111 = LD(x1, y1, z1);
    #undef LD
    float r[8];
    const unsigned int* a000 = (const unsigned int*)&f000;
    const unsigned int* a001 = (const unsigned int*)&f001;
    const unsigned int* a010 = (const unsigned int*)&f010;
    const unsigned int* a011 = (const unsigned int*)&f011;
    const unsigned int* a100 = (const unsigned int*)&f100;
    const unsigned int* a101 = (const unsigned int*)&f101;
    const unsigned int* a110 = (const unsigned int*)&f110;
    const unsigned int* a111 = (const unsigned int*)&f111;
    #pragma unroll
    for (int u = 0; u < 4; ++u) {
        float c00l = bf_lo(a000[u]) * (1.f - wz) + bf_lo(a001[u]) * wz;
        float c01l = bf_lo(a010[u]) * (1.f - wz) + bf_lo(a011[u]) * wz;
        float c10l = bf_lo(a100[u]) * (1.f - wz) + bf_lo(a101[u]) * wz;
        float c11l = bf_lo(a110[u]) * (1.f - wz) + bf_lo(a111[u]) * wz;
        r[2 * u] = (c00l * (1.f - wy) + c01l * wy) * (1.f - wx) +
                   (c10l * (1.f - wy) + c11l * wy) * wx;
        float c00h = bf_hi(a000[u]) * (1.f - wz) + bf_hi(a001[u]) * wz;
        float c01h = bf_hi(a010[u]) * (1.f - wz) + bf_hi(a011[u]) * wz;
        float c10h = bf_hi(a100[u]) * (1.f - wz) + bf_hi(a101[u]) * wz;
        float c11h = bf_hi(a110[u]) * (1.f - wz) + bf_hi(a111[u]) * wz;
        r[2 * u + 1] = (c00h * (1.f - wy) + c01h * wy) * (1.f - wx) +
                       (c10h * (1.f - wy) + c11h * wy) * wx;
    }
    unsigned int* row = feats + (size_t)v * 16;
    uint4 o;
    o.x = bf16_pack2(r[0], r[1]); o.y = bf16_pack2(r[2], r[3]);
    o.z = bf16_pack2(r[4], r[5]); o.w = bf16_pack2(r[6], r[7]);
    *(uint4*)(row + q * 4) = o;
    if (q == 0) {
        uint4 o2;
        o2.x = bf16_pack2(px * (1.0f / 128.0f), py * (1.0f / 128.0f));
        o2.y = bf16_pack2(pz * (1.0f / 128.0f), 0.0f);
        o2.z = 0u; o2.w = 0u;
        *(uint4*)(row + 8) = o2;
        *(uint4*)(row + 12) = make_uint4(0u, 0u, 0u, 0u);
    }
}

// ---------------------------------------------------------------------------
// CSR gather-sum over bf16 rows (stride SU uints). NCH=SU/4 threads per
// vertex, each owns a uint4 (8 ch) chunk; fp32 accumulate, scaled by
// invdeg[v] (folded here so the layer GEMM is a single concat-K matmul),
// bf16 output. 4x unrolled edge loop: 4 independent row gathers in flight
// to hide L3 latency (these kernels are latency-bound, not BW-bound).
template <int SU>
__global__ __launch_bounds__(256) void k_gather16(const unsigned int* __restrict__ x,
                                                  const int* __restrict__ rowStart,
                                                  const int* __restrict__ csrSrc,
                                                  const float* __restrict__ invdeg,
                                                  unsigned int* __restrict__ nb, int nv) {
    constexpr int NCH = SU / 4;
    int t = blockIdx.x * 256 + threadIdx.x;
    int v = t / NCH;
    if (v >= nv) return;
    int ch = t - v * NCH;
    int beg = rowStart[v];
    int end = rowStart[v + 1];
    float a0 = 0.f, a1 = 0.f, a2 = 0.f, a3 = 0.f, a4 = 0.f, a5 = 0.f, a6 = 0.f, a7 = 0.f;
    int j = beg;
    for (; j + 3 < end; j += 4) {
        int s0 = csrSrc[j];
        int s1 = csrSrc[j + 1];
        int s2 = csrSrc[j + 2];
        int s3 = csrSrc[j + 3];
        uint4 q0 = ((const uint4*)(x + (size_t)s0 * SU))[ch];
        uint4 q1 = ((const uint4*)(x + (size_t)s1 * SU))[ch];
        uint4 q2 = ((const uint4*)(x + (size_t)s2 * SU))[ch];
        uint4 q3 = ((const uint4*)(x + (size_t)s3 * SU))[ch];
        a0 += bf_lo(q0.x); a1 += bf_hi(q0.x);
        a2 += bf_lo(q0.y); a3 += bf_hi(q0.y);
        a4 += bf_lo(q0.z); a5 += bf_hi(q0.z);
        a6 += bf_lo(q0.w); a7 += bf_hi(q0.w);
        a0 += bf_lo(q1.x); a1 += bf_hi(q1.x);
        a2 += bf_lo(q1.y); a3 += bf_hi(q1.y);
        a4 += bf_lo(q1.z); a5 += bf_hi(q1.z);
        a6 += bf_lo(q1.w); a7 += bf_hi(q1.w);
        a0 += bf_lo(q2.x); a1 += bf_hi(q2.x);
        a2 += bf_lo(q2.y); a3 += bf_hi(q2.y);
        a4 += bf_lo(q2.z); a5 += bf_hi(q2.z);
        a6 += bf_lo(q2.w); a7 += bf_hi(q2.w);
        a0 += bf_lo(q3.x); a1 += bf_hi(q3.x);
        a2 += bf_lo(q3.y); a3 += bf_hi(q3.y);
        a4 += bf_lo(q3.z); a5 += bf_hi(q3.z);
        a6 += bf_lo(q3.w); a7 += bf_hi(q3.w);
    }
    for (; j < end; ++j) {
        int s = csrSrc[j];
        uint4 q = ((const uint4*)(x + (size_t)s * SU))[ch];
        a0 += bf_lo(q.x); a1 += bf_hi(q.x);
        a2 += bf_lo(q.y); a3 += bf_hi(q.y);
        a4 += bf_lo(q.z); a5 += bf_hi(q.z);
        a6 += bf_lo(q.w); a7 += bf_hi(q.w);
    }
    const float id = invdeg[v];
    uint4 o;
    o.x = bf16_pack2(a0 * id, a1 * id); o.y = bf16_pack2(a2 * id, a3 * id);
    o.z = bf16_pack2(a4 * id, a5 * id); o.w = bf16_pack2(a6 * id, a7 * id);
    ((uint4*)(nb + (size_t)v * SU))[ch] = o;
}

// ---------------------------------------------------------------------------
// MFMA edge-conv dense part: out = leakyrelu([x | nb_scaled] @ [[Ws],[Wn]] + b).
// A frag: lane row = l&15, 8 contiguous k at (l>>4)*8 -> one 16B global load.
// B frag: lane col = l&15, same k slice -> one 16B LDS read.
// D: col = lane&15, row = (lane>>4)*4 + reg  [m89-verified mapping].
// PREMUL (layer 2 only): also emit z[v] = act(h3[v]) @ Wn3 (64->3) — the 16
// lanes sharing a kg group jointly hold a full output row; 4-step shfl_xor
// reduction replaces the separate k_premul pass over 25.6 MB.
template <int KX, int COUT, bool REMAP0, int VALID_CIN, bool PREMUL>
__global__ __launch_bounds__(256) void k_layer_mfma(const unsigned int* __restrict__ x,
                                                    const unsigned int* __restrict__ nbs,
                                                    const float* __restrict__ Ws,
                                                    const float* __restrict__ Wn,
                                                    const float* __restrict__ bias,
                                                    unsigned int* __restrict__ out, int nv,
                                                    const float* __restrict__ Wn3,
                                                    unsigned int* __restrict__ zout) {
    constexpr int KTOT = 2 * KX;
    constexpr int KW = KTOT + 8;      // LDS row stride (bf16 elems), bank-rotating
    constexpr int NT = COUT / 16;     // n-tiles per wave
    constexpr int MT = 2;             // m-tiles per wave (32 vertices)
    constexpr int SXU = KX / 2;       // input row stride in uints
    constexpr int KS = KX / 32;       // k-steps per source
    __shared__ __align__(16) unsigned short bt[COUT * KW];
    __shared__ float wn3_s[192];

    // Build transposed bf16 weight block: bt[c][kk], kk<KX -> Ws, else Wn.
    for (int i = threadIdx.x; i < COUT * KTOT; i += 256) {
        int c = i / KTOT;
        int kk = i - c * KTOT;
        int j = (kk < KX) ? kk : kk - KX;
        const float* W = (kk < KX) ? Ws : Wn;
        float w = 0.f;
        if (j < VALID_CIN) {
            int sr = REMAP0 ? ((j < 16) ? (j + 3) : (j - 16)) : j;
            w = W[sr * COUT + c];
        }
        bt[c * KW + kk] = bf16_1(w);
    }
    if constexpr (PREMUL) {
        if (threadIdx.x < 192) wn3_s[threadIdx.x] = Wn3[threadIdx.x];
    }
    __syncthreads();

    const int lane = threadIdx.x & 63;
    const int wid = threadIdx.x >> 6;
    const int v0 = blockIdx.x * (4 * MT * 16) + wid * (MT * 16);
    const int row = lane & 15;
    const int kg = lane >> 4;         // k-subgroup: 8 contiguous k at kg*8

    f4_t acc[MT][NT] = {};

    #pragma unroll
    for (int ks = 0; ks < 2 * KS; ++ks) {
        const unsigned int* src = (ks < KS) ? x : nbs;
        const int kbase = (ks < KS) ? ks * 32 : (ks - KS) * 32;
        bf8_t afrag[MT];
        #pragma unroll
        for (int mt = 0; mt < MT; ++mt) {
            int v = v0 + mt * 16 + row;
            v = min(v, nv - 1);       // clamp: duplicate row, results masked at store
            afrag[mt] = *(const bf8_t*)(src + (size_t)v * SXU + ((kbase + kg * 8) >> 1));
        }
        #pragma unroll
        for (int nt = 0; nt < NT; ++nt) {
            bf8_t bfrag = *(const bf8_t*)(bt + (nt * 16 + row) * KW + ks * 32 + kg * 8);
            #pragma unroll
            for (int mt = 0; mt < MT; ++mt)
                acc[mt][nt] = __builtin_amdgcn_mfma_f32_16x16x32_bf16(afrag[mt], bfrag,
                                                                      acc[mt][nt], 0, 0, 0);
        }
    }

    // Epilogue: bias + leaky relu, bf16 2B stores; optional fused premul.
    unsigned short* po = (unsigned short*)out;
    float bq[NT];
    #pragma unroll
    for (int nt = 0; nt < NT; ++nt) bq[nt] = bias[nt * 16 + row];
    #pragma unroll
    for (int mt = 0; mt < MT; ++mt) {
        #pragma unroll
        for (int r = 0; r < 4; ++r) {
            const int v = v0 + mt * 16 + kg * 4 + r;
            float tv[NT];
            #pragma unroll
            for (int nt = 0; nt < NT; ++nt) {
                float t = acc[mt][nt][r] + bq[nt];
                t = (t >= 0.f) ? t : SLOPE * t;
                tv[nt] = t;
                if (v < nv) po[(size_t)v * COUT + nt * 16 + row] = bf16_1(t);
            }
            if constexpr (PREMUL) {
                float z0 = 0.f, z1 = 0.f, z2 = 0.f;
                #pragma unroll
                for (int nt = 0; nt < NT; ++nt) {
                    const float* wr = wn3_s + (nt * 16 + row) * 3;
                    z0 += tv[nt] * wr[0];
                    z1 += tv[nt] * wr[1];
                    z2 += tv[nt] * wr[2];
                }
                #pragma unroll
                for (int m = 1; m < 16; m <<= 1) {
                    z0 += __shfl_xor(z0, m);
                    z1 += __shfl_xor(z1, m);
                    z2 += __shfl_xor(z2, m);
                }
                if (row == 0 && v < nv) {
                    uint2 o;
                    o.x = bf16_pack2(z0, z1);
                    o.y = bf16_pack2(z2, 0.f);
                    *(uint2*)(zout + (size_t)v * 2) = o;
                }
            }
        }
    }
}

// Final (fused z-gather): out = verts + SCALE*(h3@Ws3 + gather(z)*inv_deg + b3)
__global__ __launch_bounds__(256) void k_final(const unsigned int* __restrict__ h,
                                               const unsigned int* __restrict__ z,
                                               const int* __restrict__ rowStart,
                                               const int* __restrict__ csrSrc,
                                               const float* __restrict__ invdeg,
                                               const float* __restrict__ ws,
                                               const float* __restrict__ b,
                                               const float* __restrict__ verts,
                                               float* __restrict__ out, int nv) {
    __shared__ float w_s[64 * 3];
    if (threadIdx.x < 64 * 3) w_s[threadIdx.x] = ws[threadIdx.x];
    __syncthreads();
    int v = blockIdx.x * 256 + threadIdx.x;
    if (v >= nv) return;
    // neighbor gather of premultiplied z (800 KB, L2-resident), 4x unrolled
    float n0 = 0.f, n1 = 0.f, n2 = 0.f;
    {
        int beg = rowStart[v];
        int end = rowStart[v + 1];
        int j = beg;
        for (; j + 3 < end; j += 4) {
            int s0 = csrSrc[j];
            int s1 = csrSrc[j + 1];
            int s2 = csrSrc[j + 2];
            int s3 = csrSrc[j + 3];
            uint2 q0 = *(const uint2*)(z + (size_t)s0 * 2);
            uint2 q1 = *(const uint2*)(z + (size_t)s1 * 2);
            uint2 q2 = *(const uint2*)(z + (size_t)s2 * 2);
            uint2 q3 = *(const uint2*)(z + (size_t)s3 * 2);
            n0 += bf_lo(q0.x); n1 += bf_hi(q0.x); n2 += bf_lo(q0.y);
            n0 += bf_lo(q1.x); n1 += bf_hi(q1.x); n2 += bf_lo(q1.y);
            n0 += bf_lo(q2.x); n1 += bf_hi(q2.x); n2 += bf_lo(q2.y);
            n0 += bf_lo(q3.x); n1 += bf_hi(q3.x); n2 += bf_lo(q3.y);
        }
        for (; j < end; ++j) {
            int s = csrSrc[j];
            uint2 q = *(const uint2*)(z + (size_t)s * 2);
            n0 += bf_lo(q.x); n1 += bf_hi(q.x); n2 += bf_lo(q.y);
        }
    }
    const uint4* hr = (const uint4*)(h + (size_t)v * 32);
    float a0 = b[0], a1 = b[1], a2 = b[2];
    #pragma unroll
    for (int q = 0; q < 8; ++q) {
        uint4 hv = hr[q];
        float f[8] = {bf_lo(hv.x), bf_hi(hv.x), bf_lo(hv.y), bf_hi(hv.y),
                      bf_lo(hv.z), bf_hi(hv.z), bf_lo(hv.w), bf_hi(hv.w)};
        #pragma unroll
        for (int i = 0; i < 8; ++i) {
            int k = q * 8 + i;
            a0 += f[i] * w_s[k * 3 + 0];
            a1 += f[i] * w_s[k * 3 + 1];
            a2 += f[i] * w_s[k * 3 + 2];
        }
    }
    float id = invdeg[v];
    a0 += n0 * id; a1 += n1 * id; a2 += n2 * id;
    out[(size_t)v * 3 + 0] = verts[(size_t)v * 3 + 0] + SCALE * a0;
    out[(size_t)v * 3 + 1] = verts[(size_t)v * 3 + 1] + SCALE * a1;
    out[(size_t)v * 3 + 2] = verts[(size_t)v * 3 + 2] + SCALE * a2;
}

// ---------------------------------------------------------------------------
extern "C" void kernel_launch(void* const* d_in, const int* in_sizes, int n_in,
                              void* d_out, int out_size, void* d_ws, size_t ws_size,
                              hipStream_t stream) {
    const float* img   = (const float*)d_in[0];
    const float* verts = (const float*)d_in[1];
    const int*   esrc  = (const int*)d_in[2];
    const int*   edst  = (const int*)d_in[3];
    const float* ws0 = (const float*)d_in[4];
    const float* wn0 = (const float*)d_in[5];
    const float* b0  = (const float*)d_in[6];
    const float* ws1 = (const float*)d_in[7];
    const float* wn1 = (const float*)d_in[8];
    const float* b1  = (const float*)d_in[9];
    const float* ws2 = (const float*)d_in[10];
    const float* wn2 = (const float*)d_in[11];
    const float* b2  = (const float*)d_in[12];
    const float* ws3 = (const float*)d_in[13];
    const float* wn3 = (const float*)d_in[14];
    const float* b3  = (const float*)d_in[15];

    const int nv = in_sizes[1] / 3;
    const int ne = in_sizes[2];

    char* base = (char*)d_ws;
    size_t off = 0;
    auto alloc = [&](size_t bytes) -> void* {
        off = (off + 255) & ~(size_t)255;
        void* p = base + off;
        off += bytes;
        return p;
    };
    float* invdeg   = (float*)alloc((size_t)nv * 4);
    int*   rowStart = (int*)alloc((size_t)(nv + 1) * 4);
    int*   bucketCount  = (int*)alloc(256 * 4);
    int*   bucketBase   = (int*)alloc(257 * 4);
    int*   bucketCursor = (int*)alloc(256 * 4);
    int*   csrSrc   = (int*)alloc((size_t)ne * 4);
    unsigned int* A   = (unsigned int*)alloc((size_t)nv * 32 * 4);  // feats(16u) then h2(32u)
    unsigned int* B   = (unsigned int*)alloc((size_t)nv * 32 * 4);  // h1(16u) then h3(32u)
    unsigned int* NBu = (unsigned int*)alloc((size_t)nv * 32 * 4);  // bf16 neighbor sums
    unsigned int* Z   = (unsigned int*)alloc((size_t)nv * 2 * 4);   // bf16 premultiplied
    unsigned int* timg = (unsigned int*)alloc((size_t)VOL * 16 * 2);
    unsigned int* pairs = (unsigned int*)NBu;  // alias: ne*4 <= nv*32*4 bytes

    auto blocks = [](long long n) { return (int)((n + 255) / 256); };
    const int nbuckets = (nv + 511) >> 9;
    const int lb = (nv + 127) / 128;  // k_layer_mfma: 128 vertices per block

    // Image transpose (independent of CSR build)
    k_transpose<<<(GRIDSZ * GRIDSZ * 32 * 4) / 256, 256, 0, stream>>>(img, timg);

    // CSR build: bucket histogram -> scan -> bucketing -> per-bucket sort
    hipMemsetAsync(bucketCount, 0, 256 * 4, stream);
    k_hist<<<(ne + HEPB - 1) / HEPB, 256, 0, stream>>>(edst, bucketCount, ne);
    k_scan256<<<1, 256, 0, stream>>>(bucketCount, bucketBase, bucketCursor, rowStart, nbuckets, nv, ne);
    k_bucket<<<(ne + EPB - 1) / EPB, 256, 0, stream>>>(esrc, edst, bucketCursor, pairs, ne);
    k_binsort<<<nbuckets, 256, 0, stream>>>(pairs, bucketBase, rowStart, invdeg, csrSrc, nv);

    // Features (channel-last bf16 volume) -> bf16 feats
    k_sample<<<blocks((long long)nv * 2), 256, 0, stream>>>(timg, verts, A, nv);

    // Layer 0: 19 -> 32 (feats stride 16u, KX=32)
    k_gather16<16><<<blocks((long long)nv * 4), 256, 0, stream>>>(A, rowStart, csrSrc, invdeg, NBu, nv);
    k_layer_mfma<32, 32, true, 19, false><<<lb, 256, 0, stream>>>(
        A, NBu, ws0, wn0, b0, B, nv, nullptr, nullptr);

    // Layer 1: 32 -> 64 (h1 stride 16u, KX=32)
    k_gather16<16><<<blocks((long long)nv * 4), 256, 0, stream>>>(B, rowStart, csrSrc, invdeg, NBu, nv);
    k_layer_mfma<32, 64, false, 32, false><<<lb, 256, 0, stream>>>(
        B, NBu, ws1, wn1, b1, A, nv, nullptr, nullptr);

    // Layer 2: 64 -> 64 (h2 stride 32u, KX=64), fused premul z = h3 @ Wn3
    k_gather16<32><<<blocks((long long)nv * 8), 256, 0, stream>>>(A, rowStart, csrSrc, invdeg, NBu, nv);
    k_layer_mfma<64, 64, false, 64, true><<<lb, 256, 0, stream>>>(
        A, NBu, ws2, wn2, b2, B, nv, wn3, Z);

    // Layer 3: fused gather+final update
    k_final<<<blocks(nv), 256, 0, stream>>>(
        B, Z, rowStart, csrSrc, invdeg, ws3, b3, verts, (float*)d_out, nv);
}

// Round 3
// 454.327 us; speedup vs baseline: 1.1514x; 1.0115x over previous
//
#include <hip/hip_runtime.h>

// Problem constants (from reference)
#define C_IMG 16
#define GRIDSZ 128
#define VOL (GRIDSZ * GRIDSZ * GRIDSZ)
#define SLOPE 0.3f
#define SCALE 0.1f
#define EPB 4096         // edges per k_bucket block
#define HEPB 16384       // edges per k_hist section block
#define TBLOCKS 8192     // transpose blocks in fused k_pre
#define BIN_CAP 16384    // max edges per 512-vertex bucket (mean 8192, sd ~90)

using f4_t  = __attribute__((ext_vector_type(4))) float;
using bf8_t = __attribute__((ext_vector_type(8))) short;

// bf16 helpers (manual, RNE pack / shift unpack)
__device__ __forceinline__ unsigned int bf16_pack2(float a, float b) {
    unsigned int ua = __float_as_uint(a);
    ua = (ua + 0x7FFFu + ((ua >> 16) & 1u)) >> 16;
    unsigned int ub = __float_as_uint(b);
    ub = (ub + 0x7FFFu + ((ub >> 16) & 1u)) >> 16;
    return ua | (ub << 16);
}
__device__ __forceinline__ unsigned short bf16_1(float a) {
    unsigned int ua = __float_as_uint(a);
    return (unsigned short)((ua + 0x7FFFu + ((ua >> 16) & 1u)) >> 16);
}
__device__ __forceinline__ float bf_lo(unsigned int u) { return __uint_as_float(u << 16); }
__device__ __forceinline__ float bf_hi(unsigned int u) { return __uint_as_float(u & 0xFFFF0000u); }

// ---------------------------------------------------------------------------
// Fused: image transpose (blocks [0,TBLOCKS)) || dst-bucket histogram
// (blocks [TBLOCKS, ...)). Independent outputs; saves a dispatch and runs
// the small hist under the transpose's shadow.
__global__ __launch_bounds__(256) void k_pre(const float* __restrict__ img,
                                             unsigned int* __restrict__ timg,
                                             const int* __restrict__ edst,
                                             int* __restrict__ bucketCount, int ne) {
    __shared__ int h[256];
    const int tid = threadIdx.x;
    if (blockIdx.x < TBLOCKS) {
        // transpose: img[16][128][128][128] fp32 -> timg[x][y][z][16] bf16
        const int t = blockIdx.x * 256 + tid;
        const int q  = t & 3;
        const int z4 = (t >> 2) & 31;
        const int xy = t >> 7;
        const int z0 = z4 * 4;
        const int c0 = q * 4;
        const size_t base = (size_t)xy * GRIDSZ + z0;
        float4 v0 = *(const float4*)(img + (size_t)(c0 + 0) * VOL + base);
        float4 v1 = *(const float4*)(img + (size_t)(c0 + 1) * VOL + base);
        float4 v2 = *(const float4*)(img + (size_t)(c0 + 2) * VOL + base);
        float4 v3 = *(const float4*)(img + (size_t)(c0 + 3) * VOL + base);
        #pragma unroll
        for (int j = 0; j < 4; ++j) {
            float f0 = (j == 0) ? v0.x : (j == 1) ? v0.y : (j == 2) ? v0.z : v0.w;
            float f1 = (j == 0) ? v1.x : (j == 1) ? v1.y : (j == 2) ? v1.z : v1.w;
            float f2 = (j == 0) ? v2.x : (j == 1) ? v2.y : (j == 2) ? v2.z : v2.w;
            float f3 = (j == 0) ? v3.x : (j == 1) ? v3.y : (j == 2) ? v3.z : v3.w;
            uint2 o;
            o.x = bf16_pack2(f0, f1);
            o.y = bf16_pack2(f2, f3);
            *(uint2*)(timg + (size_t)(xy * GRIDSZ + z0 + j) * 8 + q * 2) = o;
        }
    } else {
        // histogram of dst buckets (dst>>9)
        h[tid] = 0;
        __syncthreads();
        const int base = (blockIdx.x - TBLOCKS) * HEPB;
        const int n = min(HEPB, ne - base);
        for (int i = tid; i < n; i += 256)
            atomicAdd(&h[((unsigned)edst[base + i]) >> 9], 1);
        __syncthreads();
        if (h[tid]) atomicAdd(&bucketCount[tid], h[tid]);
    }
}

// Bucketing pass with LOCAL exclusive scan of bucketCount (replaces the
// separate 1-block k_scan256 dispatch). bucketCursor is zero-initialized;
// global position = localBase[b] + atomicAdd(cursor[b], h).
// Packed pair: (src<<9)|(dst&511) — src<2^17.
__global__ __launch_bounds__(256) void k_bucket(const int* __restrict__ esrc,
                                                const int* __restrict__ edst,
                                                const int* __restrict__ bucketCount,
                                                int* __restrict__ bucketCursor,
                                                unsigned int* __restrict__ pairs,
                                                int* __restrict__ rowStart,
                                                int ne, int nv) {
    __shared__ unsigned int hist[256];
    __shared__ unsigned int pref[256];
    __shared__ unsigned int curs[256];
    __shared__ unsigned int gbase[256];
    __shared__ int bb[256];
    __shared__ unsigned int stage_v[EPB];
    __shared__ unsigned char stage_b[EPB];
    const int tid = threadIdx.x;
    const int base = blockIdx.x * EPB;
    const int n = min(EPB, ne - base);
    if (blockIdx.x == 0 && tid == 0) rowStart[nv] = ne;
    // local scan of global bucket counts -> exclusive base
    const int c = bucketCount[tid];
    bb[tid] = c;
    hist[tid] = 0;
    __syncthreads();
    #pragma unroll
    for (int off = 1; off < 256; off <<= 1) {
        int t = (tid >= off) ? bb[tid - off] : 0;
        __syncthreads();
        bb[tid] += t;
        __syncthreads();
    }
    const int baseb = bb[tid] - c;
    // local histogram of this block's edges
    for (int i = tid; i < n; i += 256)
        atomicAdd(&hist[((unsigned)edst[base + i]) >> 9], 1u);
    __syncthreads();
    const unsigned int h = hist[tid];
    pref[tid] = h;
    __syncthreads();
    #pragma unroll
    for (int off = 1; off < 256; off <<= 1) {
        unsigned int t = (tid >= off) ? pref[tid - off] : 0;
        __syncthreads();
        pref[tid] += t;
        __syncthreads();
    }
    const unsigned int excl = pref[tid] - h;
    gbase[tid] = h ? (unsigned int)(baseb + atomicAdd(&bucketCursor[tid], (int)h)) : 0u;
    __syncthreads();
    pref[tid] = excl;
    curs[tid] = excl;
    __syncthreads();
    for (int i = tid; i < n; i += 256) {
        unsigned int d = (unsigned)edst[base + i];
        unsigned int s = (unsigned)esrc[base + i];
        unsigned int p = atomicAdd(&curs[d >> 9], 1u);
        stage_v[p] = (s << 9) | (d & 511u);
        stage_b[p] = (unsigned char)(d >> 9);
    }
    __syncthreads();
    for (int i = tid; i < n; i += 256) {
        unsigned int b = stage_b[i];
        pairs[gbase[b] + (unsigned)i - pref[b]] = stage_v[i];
    }
}

// Within-bucket sort; bucket bounds from a local scan of bucketCount.
__global__ __launch_bounds__(256) void k_binsort(const unsigned int* __restrict__ pairs,
                                                 const int* __restrict__ bucketCount,
                                                 int* __restrict__ rowStart,
                                                 float* __restrict__ invdeg,
                                                 int* __restrict__ csrSrc, int nv) {
    __shared__ int deg_s[512];
    __shared__ int rs_s[512];
    __shared__ int cur_s[512];
    __shared__ int scan_s[256];
    __shared__ int bb[256];
    __shared__ int outbuf[BIN_CAP];
    const int tid = threadIdx.x;
    const int b = blockIdx.x;
    const int vbase = b << 9;
    if (vbase >= nv) return;
    const int nvb = min(512, nv - vbase);
    // local scan for this bucket's global range
    const int c = bucketCount[tid];
    bb[tid] = c;
    deg_s[tid] = 0;
    deg_s[tid + 256] = 0;
    __syncthreads();
    #pragma unroll
    for (int off = 1; off < 256; off <<= 1) {
        int t = (tid >= off) ? bb[tid - off] : 0;
        __syncthreads();
        bb[tid] += t;
        __syncthreads();
    }
    const int cntb = bucketCount[b];
    const int ge = bb[b];
    const int gs = ge - cntb;
    const int count = cntb;
    // pass 1: degrees
    for (int i = tid; i < count; i += 256) {
        unsigned int p = pairs[gs + i];
        atomicAdd(&deg_s[p & 511u], 1);
    }
    __syncthreads();
    // scan 512 degrees (2 per thread)
    const int d0 = deg_s[2 * tid];
    const int d1 = deg_s[2 * tid + 1];
    const int ps = d0 + d1;
    scan_s[tid] = ps;
    __syncthreads();
    #pragma unroll
    for (int off = 1; off < 256; off <<= 1) {
        int t = (tid >= off) ? scan_s[tid - off] : 0;
        __syncthreads();
        scan_s[tid] += t;
        __syncthreads();
    }
    const int epair = scan_s[tid] - ps;
    rs_s[2 * tid] = epair;
    rs_s[2 * tid + 1] = epair + d0;
    cur_s[2 * tid] = epair;
    cur_s[2 * tid + 1] = epair + d0;
    #pragma unroll
    for (int u = 0; u < 2; ++u) {
        int idx = 2 * tid + u;
        if (idx < nvb) {
            rowStart[vbase + idx] = gs + rs_s[idx];
            int d = deg_s[idx];
            invdeg[vbase + idx] = 1.0f / (float)(d > 1 ? d : 1);
        }
    }
    __syncthreads();
    // pass 2: scatter
    if (count <= BIN_CAP) {
        for (int i = tid; i < count; i += 256) {
            unsigned int p = pairs[gs + i];
            int pos = atomicAdd(&cur_s[p & 511u], 1);
            outbuf[pos] = (int)(p >> 9);
        }
        __syncthreads();
        for (int i = tid; i < count; i += 256) csrSrc[gs + i] = outbuf[i];
    } else {
        // statistically unreachable; uncoalesced but correct
        for (int i = tid; i < count; i += 256) {
            unsigned int p = pairs[gs + i];
            int pos = atomicAdd(&cur_s[p & 511u], 1);
            csrSrc[gs + pos] = (int)(p >> 9);
        }
    }
}

// ---------------------------------------------------------------------------
// Trilinear sample -> bf16 feats rows, stride 16 uints (32 bf16 cols):
// cols 0..15 = channels, 16..18 = verts/128, 19..31 = 0.
__global__ __launch_bounds__(256) void k_sample(const unsigned int* __restrict__ timg,
                                                const float* __restrict__ verts,
                                                unsigned int* __restrict__ feats, int nv) {
    int t = blockIdx.x * 256 + threadIdx.x;
    int v = t >> 1;
    int q = t & 1;          // channel group: q*8 .. q*8+7
    if (v >= nv) return;
    float px = verts[v * 3 + 0];
    float py = verts[v * 3 + 1];
    float pz = verts[v * 3 + 2];
    float cx = fminf(fmaxf(px, 0.0f), 127.0f);
    float cy = fminf(fmaxf(py, 0.0f), 127.0f);
    float cz = fminf(fmaxf(pz, 0.0f), 127.0f);
    float fx = floorf(cx), fy = floorf(cy), fz = floorf(cz);
    int x0 = (int)fx, y0 = (int)fy, z0 = (int)fz;
    int x1 = min(x0 + 1, 127), y1 = min(y0 + 1, 127), z1 = min(z0 + 1, 127);
    float wx = cx - fx, wy = cy - fy, wz = cz - fz;
    const int qo = q * 4;
    #define LD(X, Y, Z) (*(const uint4*)(timg + ((size_t)((((X) << 7) + (Y)) << 7) + (size_t)(Z)) * 8 + qo))
    uint4 f000 = LD(x0, y0, z0), f001 = LD(x0, y0, z1);
    uint4 f010 = LD(x0, y1, z0), f011 = LD(x0, y1, z1);
    uint4 f100 = LD(x1, y0, z0), f101 = LD(x1, y0, z1);
    uint4 f110 = LD(x1, y1, z0), f111 = LD(x1, y1, z1);
    #undef LD
    float r[8];
    const unsigned int* a000 = (const unsigned int*)&f000;
    const unsigned int* a001 = (const unsigned int*)&f001;
    const unsigned int* a010 = (const unsigned int*)&f010;
    const unsigned int* a011 = (const unsigned int*)&f011;
    const unsigned int* a100 = (const unsigned int*)&f100;
    const unsigned int* a101 = (const unsigned int*)&f101;
    const unsigned int* a110 = (const unsigned int*)&f110;
    const unsigned int* a111 = (const unsigned int*)&f111;
    #pragma unroll
    for (int u = 0; u < 4; ++u) {
        float c00l = bf_lo(a000[u]) * (1.f - wz) + bf_lo(a001[u]) * wz;
        float c01l = bf_lo(a010[u]) * (1.f - wz) + bf_lo(a011[u]) * wz;
        float c10l = bf_lo(a100[u]) * (1.f - wz) + bf_lo(a101[u]) * wz;
        float c11l = bf_lo(a110[u]) * (1.f - wz) + bf_lo(a111[u]) * wz;
        r[2 * u] = (c00l * (1.f - wy) + c01l * wy) * (1.f - wx) +
                   (c10l * (1.f - wy) + c11l * wy) * wx;
        float c00h = bf_hi(a000[u]) * (1.f - wz) + bf_hi(a001[u]) * wz;
        float c01h = bf_hi(a010[u]) * (1.f - wz) + bf_hi(a011[u]) * wz;
        float c10h = bf_hi(a100[u]) * (1.f - wz) + bf_hi(a101[u]) * wz;
        float c11h = bf_hi(a110[u]) * (1.f - wz) + bf_hi(a111[u]) * wz;
        r[2 * u + 1] = (c00h * (1.f - wy) + c01h * wy) * (1.f - wx) +
                       (c10h * (1.f - wy) + c11h * wy) * wx;
    }
    unsigned int* row = feats + (size_t)v * 16;
    uint4 o;
    o.x = bf16_pack2(r[0], r[1]); o.y = bf16_pack2(r[2], r[3]);
    o.z = bf16_pack2(r[4], r[5]); o.w = bf16_pack2(r[6], r[7]);
    *(uint4*)(row + q * 4) = o;
    if (q == 0) {
        uint4 o2;
        o2.x = bf16_pack2(px * (1.0f / 128.0f), py * (1.0f / 128.0f));
        o2.y = bf16_pack2(pz * (1.0f / 128.0f), 0.0f);
        o2.z = 0u; o2.w = 0u;
        *(uint4*)(row + 8) = o2;
        *(uint4*)(row + 12) = make_uint4(0u, 0u, 0u, 0u);
    }
}

// ---------------------------------------------------------------------------
// FUSED gather + MFMA edge-conv:
//   nb_s[vloc][*] = bf16( invdeg[v] * sum_{s in N(v)} x[s][*] )   (LDS tile)
//   out = leakyrelu([x | nb] @ [[Ws],[Wn]] + b)
// Removes the NBu global round-trip (~102 MB over 3 layers) and overlaps
// gather latency with MFMA via cross-block wave scheduling.
// A frag: lane row = l&15, 8 contiguous k at (l>>4)*8 (16B load).
// D: col = lane&15, row = (lane>>4)*4 + reg  [m89-verified mapping].
// PREMUL (layer 2): also emit z[v] = act(h3[v]) @ Wn3 via 16-lane shfl reduce.
template <int KX, int COUT, bool REMAP0, int VALID_CIN, bool PREMUL>
__global__ __launch_bounds__(256) void k_layer_fused(const unsigned int* __restrict__ x,
                                                     const int* __restrict__ rowStart,
                                                     const int* __restrict__ csrSrc,
                                                     const float* __restrict__ invdeg,
                                                     const float* __restrict__ Ws,
                                                     const float* __restrict__ Wn,
                                                     const float* __restrict__ bias,
                                                     unsigned int* __restrict__ out, int nv,
                                                     const float* __restrict__ Wn3,
                                                     unsigned int* __restrict__ zout) {
    constexpr int KTOT = 2 * KX;
    constexpr int KW = KTOT + 8;      // weight LDS row stride (bf16), bank-rotating
    constexpr int NT = COUT / 16;     // n-tiles per wave
    constexpr int MT = 2;             // m-tiles per wave (32 vertices)
    constexpr int SXU = KX / 2;       // x row stride in uints
    constexpr int KS = KX / 32;       // k-steps per source
    constexpr int VPB = 128;          // vertices per block
    constexpr int NCH = KX / 8;       // 16B chunks per gathered row
    constexpr int NBW = KX + 8;       // nb_s row stride (bf16 elems); keeps 16B align
    __shared__ __align__(16) unsigned short bt[COUT * KW];
    __shared__ __align__(16) unsigned short nb_s[VPB * NBW];
    __shared__ float wn3_s[192];

    // Stage weights: bt[c][kk], kk<KX -> Ws, else Wn.
    for (int i = threadIdx.x; i < COUT * KTOT; i += 256) {
        int c = i / KTOT;
        int kk = i - c * KTOT;
        int j = (kk < KX) ? kk : kk - KX;
        const float* W = (kk < KX) ? Ws : Wn;
        float w = 0.f;
        if (j < VALID_CIN) {
            int sr = REMAP0 ? ((j < 16) ? (j + 3) : (j - 16)) : j;
            w = W[sr * COUT + c];
        }
        bt[c * KW + kk] = bf16_1(w);
    }
    if constexpr (PREMUL) {
        if (threadIdx.x < 192) wn3_s[threadIdx.x] = Wn3[threadIdx.x];
    }

    // Gather phase: accumulate neighbor rows in registers, write bf16 to LDS.
    const int vb0 = blockIdx.x * VPB;
    for (int task = threadIdx.x; task < VPB * NCH; task += 256) {
        const int vloc = task / NCH;
        const int ch = task - vloc * NCH;
        const int v = vb0 + vloc;
        unsigned short* dst = nb_s + vloc * NBW + ch * 8;
        if (v < nv) {
            int beg = rowStart[v];
            int end = rowStart[v + 1];
            float a0 = 0.f, a1 = 0.f, a2 = 0.f, a3 = 0.f,
                  a4 = 0.f, a5 = 0.f, a6 = 0.f, a7 = 0.f;
            int j = beg;
            for (; j + 3 < end; j += 4) {
                int s0 = csrSrc[j];
                int s1 = csrSrc[j + 1];
                int s2 = csrSrc[j + 2];
                int s3 = csrSrc[j + 3];
                uint4 q0 = ((const uint4*)(x + (size_t)s0 * SXU))[ch];
                uint4 q1 = ((const uint4*)(x + (size_t)s1 * SXU))[ch];
                uint4 q2 = ((const uint4*)(x + (size_t)s2 * SXU))[ch];
                uint4 q3 = ((const uint4*)(x + (size_t)s3 * SXU))[ch];
                a0 += bf_lo(q0.x); a1 += bf_hi(q0.x);
                a2 += bf_lo(q0.y); a3 += bf_hi(q0.y);
                a4 += bf_lo(q0.z); a5 += bf_hi(q0.z);
                a6 += bf_lo(q0.w); a7 += bf_hi(q0.w);
                a0 += bf_lo(q1.x); a1 += bf_hi(q1.x);
                a2 += bf_lo(q1.y); a3 += bf_hi(q1.y);
                a4 += bf_lo(q1.z); a5 += bf_hi(q1.z);
                a6 += bf_lo(q1.w); a7 += bf_hi(q1.w);
                a0 += bf_lo(q2.x); a1 += bf_hi(q2.x);
                a2 += bf_lo(q2.y); a3 += bf_hi(q2.y);
                a4 += bf_lo(q2.z); a5 += bf_hi(q2.z);
                a6 += bf_lo(q2.w); a7 += bf_hi(q2.w);
                a0 += bf_lo(q3.x); a1 += bf_hi(q3.x);
                a2 += bf_lo(q3.y); a3 += bf_hi(q3.y);
                a4 += bf_lo(q3.z); a5 += bf_hi(q3.z);
                a6 += bf_lo(q3.w); a7 += bf_hi(q3.w);
            }
            for (; j < end; ++j) {
                int s = csrSrc[j];
                uint4 q = ((const uint4*)(x + (size_t)s * SXU))[ch];
                a0 += bf_lo(q.x); a1 += bf_hi(q.x);
                a2 += bf_lo(q.y); a3 += bf_hi(q.y);
                a4 += bf_lo(q.z); a5 += bf_hi(q.z);
                a6 += bf_lo(q.w); a7 += bf_hi(q.w);
            }
            const float id = invdeg[v];
            uint4 o;
            o.x = bf16_pack2(a0 * id, a1 * id); o.y = bf16_pack2(a2 * id, a3 * id);
            o.z = bf16_pack2(a4 * id, a5 * id); o.w = bf16_pack2(a6 * id, a7 * id);
            *(uint4*)dst = o;
        } else {
            *(uint4*)dst = make_uint4(0u, 0u, 0u, 0u);
        }
    }
    __syncthreads();

    const int lane = threadIdx.x & 63;
    const int wid = threadIdx.x >> 6;
    const int v0 = vb0 + wid * (MT * 16);
    const int row = lane & 15;
    const int kg = lane >> 4;         // k-subgroup: 8 contiguous k at kg*8

    f4_t acc[MT][NT] = {};

    #pragma unroll
    for (int ks = 0; ks < 2 * KS; ++ks) {
        bf8_t afrag[MT];
        if (ks < KS) {
            const int kbase = ks * 32;
            #pragma unroll
            for (int mt = 0; mt < MT; ++mt) {
                int v = v0 + mt * 16 + row;
                v = min(v, nv - 1);   // clamp: duplicate row, masked at store
                afrag[mt] = *(const bf8_t*)(x + (size_t)v * SXU + ((kbase + kg * 8) >> 1));
            }
        } else {
            const int kbase = (ks - KS) * 32;
            #pragma unroll
            for (int mt = 0; mt < MT; ++mt) {
                const int vloc = wid * (MT * 16) + mt * 16 + row;
                afrag[mt] = *(const bf8_t*)(nb_s + vloc * NBW + kbase + kg * 8);
            }
        }
        #pragma unroll
        for (int nt = 0; nt < NT; ++nt) {
            bf8_t bfrag = *(const bf8_t*)(bt + (nt * 16 + row) * KW + ks * 32 + kg * 8);
            #pragma unroll
            for (int mt = 0; mt < MT; ++mt)
                acc[mt][nt] = __builtin_amdgcn_mfma_f32_16x16x32_bf16(afrag[mt], bfrag,
                                                                      acc[mt][nt], 0, 0, 0);
        }
    }

    // Epilogue: bias + leaky relu, bf16 2B stores; optional fused premul.
    unsigned short* po = (unsigned short*)out;
    float bq[NT];
    #pragma unroll
    for (int nt = 0; nt < NT; ++nt) bq[nt] = bias[nt * 16 + row];
    #pragma unroll
    for (int mt = 0; mt < MT; ++mt) {
        #pragma unroll
        for (int r = 0; r < 4; ++r) {
            const int v = v0 + mt * 16 + kg * 4 + r;
            float tv[NT];
            #pragma unroll
            for (int nt = 0; nt < NT; ++nt) {
                float t = acc[mt][nt][r] + bq[nt];
                t = (t >= 0.f) ? t : SLOPE * t;
                tv[nt] = t;
                if (v < nv) po[(size_t)v * COUT + nt * 16 + row] = bf16_1(t);
            }
            if constexpr (PREMUL) {
                float z0 = 0.f, z1 = 0.f, z2 = 0.f;
                #pragma unroll
                for (int nt = 0; nt < NT; ++nt) {
                    const float* wr = wn3_s + (nt * 16 + row) * 3;
                    z0 += tv[nt] * wr[0];
                    z1 += tv[nt] * wr[1];
                    z2 += tv[nt] * wr[2];
                }
                #pragma unroll
                for (int m = 1; m < 16; m <<= 1) {
                    z0 += __shfl_xor(z0, m);
                    z1 += __shfl_xor(z1, m);
                    z2 += __shfl_xor(z2, m);
                }
                if (row == 0 && v < nv) {
                    uint2 o;
                    o.x = bf16_pack2(z0, z1);
                    o.y = bf16_pack2(z2, 0.f);
                    *(uint2*)(zout + (size_t)v * 2) = o;
                }
            }
        }
    }
}

// Final (fused z-gather): out = verts + SCALE*(h3@Ws3 + gather(z)*inv_deg + b3)
__global__ __launch_bounds__(256) void k_final(const unsigned int* __restrict__ h,
                                               const unsigned int* __restrict__ z,
                                               const int* __restrict__ rowStart,
                                               const int* __restrict__ csrSrc,
                                               const float* __restrict__ invdeg,
                                               const float* __restrict__ ws,
                                               const float* __restrict__ b,
                                               const float* __restrict__ verts,
                                               float* __restrict__ out, int nv) {
    __shared__ float w_s[64 * 3];
    if (threadIdx.x < 64 * 3) w_s[threadIdx.x] = ws[threadIdx.x];
    __syncthreads();
    int v = blockIdx.x * 256 + threadIdx.x;
    if (v >= nv) return;
    // neighbor gather of premultiplied z (800 KB, L2-resident), 4x unrolled
    float n0 = 0.f, n1 = 0.f, n2 = 0.f;
    {
        int beg = rowStart[v];
        int end = rowStart[v + 1];
        int j = beg;
        for (; j + 3 < end; j += 4) {
            int s0 = csrSrc[j];
            int s1 = csrSrc[j + 1];
            int s2 = csrSrc[j + 2];
            int s3 = csrSrc[j + 3];
            uint2 q0 = *(const uint2*)(z + (size_t)s0 * 2);
            uint2 q1 = *(const uint2*)(z + (size_t)s1 * 2);
            uint2 q2 = *(const uint2*)(z + (size_t)s2 * 2);
            uint2 q3 = *(const uint2*)(z + (size_t)s3 * 2);
            n0 += bf_lo(q0.x); n1 += bf_hi(q0.x); n2 += bf_lo(q0.y);
            n0 += bf_lo(q1.x); n1 += bf_hi(q1.x); n2 += bf_lo(q1.y);
            n0 += bf_lo(q2.x); n1 += bf_hi(q2.x); n2 += bf_lo(q2.y);
            n0 += bf_lo(q3.x); n1 += bf_hi(q3.x); n2 += bf_lo(q3.y);
        }
        for (; j < end; ++j) {
            int s = csrSrc[j];
            uint2 q = *(const uint2*)(z + (size_t)s * 2);
            n0 += bf_lo(q.x); n1 += bf_hi(q.x); n2 += bf_lo(q.y);
        }
    }
    const uint4* hr = (const uint4*)(h + (size_t)v * 32);
    float a0 = b[0], a1 = b[1], a2 = b[2];
    #pragma unroll
    for (int q = 0; q < 8; ++q) {
        uint4 hv = hr[q];
        float f[8] = {bf_lo(hv.x), bf_hi(hv.x), bf_lo(hv.y), bf_hi(hv.y),
                      bf_lo(hv.z), bf_hi(hv.z), bf_lo(hv.w), bf_hi(hv.w)};
        #pragma unroll
        for (int i = 0; i < 8; ++i) {
            int k = q * 8 + i;
            a0 += f[i] * w_s[k * 3 + 0];
            a1 += f[i] * w_s[k * 3 + 1];
            a2 += f[i] * w_s[k * 3 + 2];
        }
    }
    float id = invdeg[v];
    a0 += n0 * id; a1 += n1 * id; a2 += n2 * id;
    out[(size_t)v * 3 + 0] = verts[(size_t)v * 3 + 0] + SCALE * a0;
    out[(size_t)v * 3 + 1] = verts[(size_t)v * 3 + 1] + SCALE * a1;
    out[(size_t)v * 3 + 2] = verts[(size_t)v * 3 + 2] + SCALE * a2;
}

// ---------------------------------------------------------------------------
extern "C" void kernel_launch(void* const* d_in, const int* in_sizes, int n_in,
                              void* d_out, int out_size, void* d_ws, size_t ws_size,
                              hipStream_t stream) {
    const float* img   = (const float*)d_in[0];
    const float* verts = (const float*)d_in[1];
    const int*   esrc  = (const int*)d_in[2];
    const int*   edst  = (const int*)d_in[3];
    const float* ws0 = (const float*)d_in[4];
    const float* wn0 = (const float*)d_in[5];
    const float* b0  = (const float*)d_in[6];
    const float* ws1 = (const float*)d_in[7];
    const float* wn1 = (const float*)d_in[8];
    const float* b1  = (const float*)d_in[9];
    const float* ws2 = (const float*)d_in[10];
    const float* wn2 = (const float*)d_in[11];
    const float* b2  = (const float*)d_in[12];
    const float* ws3 = (const float*)d_in[13];
    const float* wn3 = (const float*)d_in[14];
    const float* b3  = (const float*)d_in[15];

    const int nv = in_sizes[1] / 3;
    const int ne = in_sizes[2];

    char* base = (char*)d_ws;
    size_t off = 0;
    auto alloc = [&](size_t bytes) -> void* {
        off = (off + 255) & ~(size_t)255;
        void* p = base + off;
        off += bytes;
        return p;
    };
    float* invdeg   = (float*)alloc((size_t)nv * 4);
    int*   rowStart = (int*)alloc((size_t)(nv + 1) * 4);
    int*   bcb      = (int*)alloc(512 * 4);   // [0,256)=bucketCount, [256,512)=bucketCursor
    int*   bucketCount  = bcb;
    int*   bucketCursor = bcb + 256;
    int*   csrSrc   = (int*)alloc((size_t)ne * 4);
    unsigned int* pairs = (unsigned int*)alloc((size_t)ne * 4);
    unsigned int* A   = (unsigned int*)alloc((size_t)nv * 32 * 4);  // feats(16u) then h2(32u)
    unsigned int* B   = (unsigned int*)alloc((size_t)nv * 32 * 4);  // h1(16u) then h3(32u)
    unsigned int* Z   = (unsigned int*)alloc((size_t)nv * 2 * 4);   // bf16 premultiplied
    unsigned int* timg = (unsigned int*)alloc((size_t)VOL * 16 * 2);

    auto blocks = [](long long n) { return (int)((n + 255) / 256); };
    const int nbuckets = (nv + 511) >> 9;
    const int nhb = (ne + HEPB - 1) / HEPB;
    const int lb = (nv + 127) / 128;  // fused layers: 128 vertices per block

    // counters zero (bucketCount + bucketCursor)
    hipMemsetAsync(bcb, 0, 512 * 4, stream);
    // transpose || histogram
    k_pre<<<TBLOCKS + nhb, 256, 0, stream>>>(img, timg, edst, bucketCount, ne);
    // bucket (local scan) -> per-bucket sort (local scan)
    k_bucket<<<(ne + EPB - 1) / EPB, 256, 0, stream>>>(esrc, edst, bucketCount, bucketCursor,
                                                       pairs, rowStart, ne, nv);
    k_binsort<<<nbuckets, 256, 0, stream>>>(pairs, bucketCount, rowStart, invdeg, csrSrc, nv);

    // Features (channel-last bf16 volume) -> bf16 feats
    k_sample<<<blocks((long long)nv * 2), 256, 0, stream>>>(timg, verts, A, nv);

    // Layer 0: 19 -> 32 (feats stride 16u, KX=32)
    k_layer_fused<32, 32, true, 19, false><<<lb, 256, 0, stream>>>(
        A, rowStart, csrSrc, invdeg, ws0, wn0, b0, B, nv, nullptr, nullptr);

    // Layer 1: 32 -> 64 (h1 stride 16u, KX=32)
    k_layer_fused<32, 64, false, 32, false><<<lb, 256, 0, stream>>>(
        B, rowStart, csrSrc, invdeg, ws1, wn1, b1, A, nv, nullptr, nullptr);

    // Layer 2: 64 -> 64 (h2 stride 32u, KX=64), fused premul z = h3 @ Wn3
    k_layer_fused<64, 64, false, 64, true><<<lb, 256, 0, stream>>>(
        A, rowStart, csrSrc, invdeg, ws2, wn2, b2, B, nv, wn3, Z);

    // Layer 3: fused gather+final update
    k_final<<<blocks(nv), 256, 0, stream>>>(
        B, Z, rowStart, csrSrc, invdeg, ws3, b3, verts, (float*)d_out, nv);
}

// Round 4
// 437.753 us; speedup vs baseline: 1.1950x; 1.0379x over previous
//
#include <hip/hip_runtime.h>

// Problem constants (from reference)
#define C_IMG 16
#define GRIDSZ 128
#define VOL (GRIDSZ * GRIDSZ * GRIDSZ)
#define SLOPE 0.3f
#define SCALE 0.1f
#define EPB 4096         // edges per k_bucket block
#define CAPB 12288       // fixed pair-region capacity per 512-vtx bucket (mean 8192, sd ~90)
#define BIN_CAP 16384    // binsort LDS staging capacity

using f4_t  = __attribute__((ext_vector_type(4))) float;
using bf8_t = __attribute__((ext_vector_type(8))) short;

// bf16 helpers (manual, RNE pack / shift unpack)
__device__ __forceinline__ unsigned int bf16_pack2(float a, float b) {
    unsigned int ua = __float_as_uint(a);
    ua = (ua + 0x7FFFu + ((ua >> 16) & 1u)) >> 16;
    unsigned int ub = __float_as_uint(b);
    ub = (ub + 0x7FFFu + ((ub >> 16) & 1u)) >> 16;
    return ua | (ub << 16);
}
__device__ __forceinline__ unsigned short bf16_1(float a) {
    unsigned int ua = __float_as_uint(a);
    return (unsigned short)((ua + 0x7FFFu + ((ua >> 16) & 1u)) >> 16);
}
__device__ __forceinline__ float bf_lo(unsigned int u) { return __uint_as_float(u << 16); }
__device__ __forceinline__ float bf_hi(unsigned int u) { return __uint_as_float(u & 0xFFFF0000u); }

// ---------------------------------------------------------------------------
// Image transpose: img[16][128][128][128] fp32 -> timg[x][y][z][16] bf16.
// One thread per z-PAIR: 16 coalesced float2 loads (512 B/wave/instr, all 16
// in flight) -> two complete 32 B output rows (4 uint4 stores, contiguous
// 4 KB per wave). Streaming-BW-bound by construction.
__global__ __launch_bounds__(256) void k_transpose(const float* __restrict__ img,
                                                   unsigned int* __restrict__ timg) {
    const int t = blockIdx.x * 256 + threadIdx.x;   // [0, VOL/2)
    const int zp = t & 63;                          // z pair index
    const int xy = t >> 6;                          // x*128+y
    const size_t ibase = (size_t)xy * GRIDSZ + 2 * zp;
    float2 c[16];
    #pragma unroll
    for (int ch = 0; ch < 16; ++ch)
        c[ch] = *(const float2*)(img + (size_t)ch * VOL + ibase);
    uint4 o0a, o0b, o1a, o1b;
    o0a.x = bf16_pack2(c[0].x,  c[1].x);  o0a.y = bf16_pack2(c[2].x,  c[3].x);
    o0a.z = bf16_pack2(c[4].x,  c[5].x);  o0a.w = bf16_pack2(c[6].x,  c[7].x);
    o0b.x = bf16_pack2(c[8].x,  c[9].x);  o0b.y = bf16_pack2(c[10].x, c[11].x);
    o0b.z = bf16_pack2(c[12].x, c[13].x); o0b.w = bf16_pack2(c[14].x, c[15].x);
    o1a.x = bf16_pack2(c[0].y,  c[1].y);  o1a.y = bf16_pack2(c[2].y,  c[3].y);
    o1a.z = bf16_pack2(c[4].y,  c[5].y);  o1a.w = bf16_pack2(c[6].y,  c[7].y);
    o1b.x = bf16_pack2(c[8].y,  c[9].y);  o1b.y = bf16_pack2(c[10].y, c[11].y);
    o1b.z = bf16_pack2(c[12].y, c[13].y); o1b.w = bf16_pack2(c[14].y, c[15].y);
    unsigned int* po = timg + (size_t)(xy * GRIDSZ + 2 * zp) * 8;
    *(uint4*)(po + 0)  = o0a;
    *(uint4*)(po + 4)  = o0b;
    *(uint4*)(po + 8)  = o1a;
    *(uint4*)(po + 12) = o1b;
}

// ---------------------------------------------------------------------------
// Single-pass bucketing into FIXED-CAPACITY per-bucket regions (no global
// pre-scan / histogram pass needed). Region b = pairs[b*CAPB ..). Position
// via global atomic cursor per bucket; LDS staging keeps writes coalesced.
// Packed pair: (src<<9)|(dst&511) — src<2^17.
__global__ __launch_bounds__(256) void k_bucket(const int* __restrict__ esrc,
                                                const int* __restrict__ edst,
                                                int* __restrict__ bucketCursor,
                                                unsigned int* __restrict__ pairs,
                                                int* __restrict__ rowStart,
                                                int ne, int nv) {
    __shared__ unsigned int hist[256];
    __shared__ unsigned int pref[256];
    __shared__ unsigned int curs[256];
    __shared__ unsigned int gbase[256];
    __shared__ unsigned int stage_v[EPB];
    __shared__ unsigned char stage_b[EPB];
    const int tid = threadIdx.x;
    const int base = blockIdx.x * EPB;
    const int n = min(EPB, ne - base);
    if (blockIdx.x == 0 && tid == 0) rowStart[nv] = ne;
    hist[tid] = 0;
    __syncthreads();
    for (int i = tid; i < n; i += 256)
        atomicAdd(&hist[((unsigned)edst[base + i]) >> 9], 1u);
    __syncthreads();
    const unsigned int h = hist[tid];
    pref[tid] = h;
    __syncthreads();
    #pragma unroll
    for (int off = 1; off < 256; off <<= 1) {
        unsigned int t = (tid >= off) ? pref[tid - off] : 0;
        __syncthreads();
        pref[tid] += t;
        __syncthreads();
    }
    const unsigned int excl = pref[tid] - h;
    if (h) {
        int pos = atomicAdd(&bucketCursor[tid], (int)h);
        if (pos > CAPB - (int)h) pos = CAPB - (int)h;  // statistically unreachable guard
        gbase[tid] = (unsigned int)(tid * CAPB + pos);
    } else {
        gbase[tid] = 0u;
    }
    __syncthreads();
    pref[tid] = excl;
    curs[tid] = excl;
    __syncthreads();
    for (int i = tid; i < n; i += 256) {
        unsigned int d = (unsigned)edst[base + i];
        unsigned int s = (unsigned)esrc[base + i];
        unsigned int p = atomicAdd(&curs[d >> 9], 1u);
        stage_v[p] = (s << 9) | (d & 511u);
        stage_b[p] = (unsigned char)(d >> 9);
    }
    __syncthreads();
    for (int i = tid; i < n; i += 256) {
        unsigned int b = stage_b[i];
        pairs[gbase[b] + (unsigned)i - pref[b]] = stage_v[i];
    }
}

// Within-bucket sort. Bucket counts = final cursors; dense CSR offset from a
// local scan of those counts. Reads from fixed region b*CAPB, writes dense
// csrSrc + rowStart + invdeg.
__global__ __launch_bounds__(256) void k_binsort(const unsigned int* __restrict__ pairs,
                                                 const int* __restrict__ bucketCursor,
                                                 int* __restrict__ rowStart,
                                                 float* __restrict__ invdeg,
                                                 int* __restrict__ csrSrc, int nv) {
    __shared__ int deg_s[512];
    __shared__ int rs_s[512];
    __shared__ int cur_s[512];
    __shared__ int scan_s[256];
    __shared__ int bb[256];
    __shared__ int outbuf[BIN_CAP];
    const int tid = threadIdx.x;
    const int b = blockIdx.x;
    const int vbase = b << 9;
    if (vbase >= nv) return;
    const int nvb = min(512, nv - vbase);
    // local scan of clamped counts -> dense CSR base
    const int c = min(bucketCursor[tid], CAPB);
    bb[tid] = c;
    deg_s[tid] = 0;
    deg_s[tid + 256] = 0;
    __syncthreads();
    #pragma unroll
    for (int off = 1; off < 256; off <<= 1) {
        int t = (tid >= off) ? bb[tid - off] : 0;
        __syncthreads();
        bb[tid] += t;
        __syncthreads();
    }
    const int count = min(bucketCursor[b], CAPB);
    const int gs = bb[b] - count;                 // dense CSR start of this bucket
    const unsigned int* pbase = pairs + (size_t)b * CAPB;
    // pass 1: degrees
    for (int i = tid; i < count; i += 256) {
        unsigned int p = pbase[i];
        atomicAdd(&deg_s[p & 511u], 1);
    }
    __syncthreads();
    // scan 512 degrees (2 per thread)
    const int d0 = deg_s[2 * tid];
    const int d1 = deg_s[2 * tid + 1];
    const int ps = d0 + d1;
    scan_s[tid] = ps;
    __syncthreads();
    #pragma unroll
    for (int off = 1; off < 256; off <<= 1) {
        int t = (tid >= off) ? scan_s[tid - off] : 0;
        __syncthreads();
        scan_s[tid] += t;
        __syncthreads();
    }
    const int epair = scan_s[tid] - ps;
    rs_s[2 * tid] = epair;
    rs_s[2 * tid + 1] = epair + d0;
    cur_s[2 * tid] = epair;
    cur_s[2 * tid + 1] = epair + d0;
    #pragma unroll
    for (int u = 0; u < 2; ++u) {
        int idx = 2 * tid + u;
        if (idx < nvb) {
            rowStart[vbase + idx] = gs + rs_s[idx];
            int d = deg_s[idx];
            invdeg[vbase + idx] = 1.0f / (float)(d > 1 ? d : 1);
        }
    }
    __syncthreads();
    // pass 2: scatter (count <= CAPB < BIN_CAP always)
    for (int i = tid; i < count; i += 256) {
        unsigned int p = pbase[i];
        int pos = atomicAdd(&cur_s[p & 511u], 1);
        outbuf[pos] = (int)(p >> 9);
    }
    __syncthreads();
    for (int i = tid; i < count; i += 256) csrSrc[gs + i] = outbuf[i];
}

// ---------------------------------------------------------------------------
// Trilinear sample -> bf16 feats rows, stride 16 uints (32 bf16 cols):
// cols 0..15 = channels, 16..18 = verts/128, 19..31 = 0.
__global__ __launch_bounds__(256) void k_sample(const unsigned int* __restrict__ timg,
                                                const float* __restrict__ verts,
                                                unsigned int* __restrict__ feats, int nv) {
    int t = blockIdx.x * 256 + threadIdx.x;
    int v = t >> 1;
    int q = t & 1;          // channel group: q*8 .. q*8+7
    if (v >= nv) return;
    float px = verts[v * 3 + 0];
    float py = verts[v * 3 + 1];
    float pz = verts[v * 3 + 2];
    float cx = fminf(fmaxf(px, 0.0f), 127.0f);
    float cy = fminf(fmaxf(py, 0.0f), 127.0f);
    float cz = fminf(fmaxf(pz, 0.0f), 127.0f);
    float fx = floorf(cx), fy = floorf(cy), fz = floorf(cz);
    int x0 = (int)fx, y0 = (int)fy, z0 = (int)fz;
    int x1 = min(x0 + 1, 127), y1 = min(y0 + 1, 127), z1 = min(z0 + 1, 127);
    float wx = cx - fx, wy = cy - fy, wz = cz - fz;
    const int qo = q * 4;
    #define LD(X, Y, Z) (*(const uint4*)(timg + ((size_t)((((X) << 7) + (Y)) << 7) + (size_t)(Z)) * 8 + qo))
    uint4 f000 = LD(x0, y0, z0), f001 = LD(x0, y0, z1);
    uint4 f010 = LD(x0, y1, z0), f011 = LD(x0, y1, z1);
    uint4 f100 = LD(x1, y0, z0), f101 = LD(x1, y0, z1);
    uint4 f110 = LD(x1, y1, z0), f111 = LD(x1, y1, z1);
    #undef LD
    float r[8];
    const unsigned int* a000 = (const unsigned int*)&f000;
    const unsigned int* a001 = (const unsigned int*)&f001;
    const unsigned int* a010 = (const unsigned int*)&f010;
    const unsigned int* a011 = (const unsigned int*)&f011;
    const unsigned int* a100 = (const unsigned int*)&f100;
    const unsigned int* a101 = (const unsigned int*)&f101;
    const unsigned int* a110 = (const unsigned int*)&f110;
    const unsigned int* a111 = (const unsigned int*)&f111;
    #pragma unroll
    for (int u = 0; u < 4; ++u) {
        float c00l = bf_lo(a000[u]) * (1.f - wz) + bf_lo(a001[u]) * wz;
        float c01l = bf_lo(a010[u]) * (1.f - wz) + bf_lo(a011[u]) * wz;
        float c10l = bf_lo(a100[u]) * (1.f - wz) + bf_lo(a101[u]) * wz;
        float c11l = bf_lo(a110[u]) * (1.f - wz) + bf_lo(a111[u]) * wz;
        r[2 * u] = (c00l * (1.f - wy) + c01l * wy) * (1.f - wx) +
                   (c10l * (1.f - wy) + c11l * wy) * wx;
        float c00h = bf_hi(a000[u]) * (1.f - wz) + bf_hi(a001[u]) * wz;
        float c01h = bf_hi(a010[u]) * (1.f - wz) + bf_hi(a011[u]) * wz;
        float c10h = bf_hi(a100[u]) * (1.f - wz) + bf_hi(a101[u]) * wz;
        float c11h = bf_hi(a110[u]) * (1.f - wz) + bf_hi(a111[u]) * wz;
        r[2 * u + 1] = (c00h * (1.f - wy) + c01h * wy) * (1.f - wx) +
                       (c10h * (1.f - wy) + c11h * wy) * wx;
    }
    unsigned int* row = feats + (size_t)v * 16;
    uint4 o;
    o.x = bf16_pack2(r[0], r[1]); o.y = bf16_pack2(r[2], r[3]);
    o.z = bf16_pack2(r[4], r[5]); o.w = bf16_pack2(r[6], r[7]);
    *(uint4*)(row + q * 4) = o;
    if (q == 0) {
        uint4 o2;
        o2.x = bf16_pack2(px * (1.0f / 128.0f), py * (1.0f / 128.0f));
        o2.y = bf16_pack2(pz * (1.0f / 128.0f), 0.0f);
        o2.z = 0u; o2.w = 0u;
        *(uint4*)(row + 8) = o2;
        *(uint4*)(row + 12) = make_uint4(0u, 0u, 0u, 0u);
    }
}

// ---------------------------------------------------------------------------
// FUSED gather + MFMA edge-conv:
//   nb_s[vloc][*] = bf16( invdeg[v] * sum_{s in N(v)} x[s][*] )   (LDS tile)
//   out = leakyrelu([x | nb] @ [[Ws],[Wn]] + b)
// A frag: lane row = l&15, 8 contiguous k at (l>>4)*8 (16B load).
// D: col = lane&15, row = (lane>>4)*4 + reg  [m89-verified mapping].
// PREMUL (layer 2): also emit z[v] = act(h3[v]) @ Wn3 via 16-lane shfl reduce.
template <int KX, int COUT, bool REMAP0, int VALID_CIN, bool PREMUL>
__global__ __launch_bounds__(256) void k_layer_fused(const unsigned int* __restrict__ x,
                                                     const int* __restrict__ rowStart,
                                                     const int* __restrict__ csrSrc,
                                                     const float* __restrict__ invdeg,
                                                     const float* __restrict__ Ws,
                                                     const float* __restrict__ Wn,
                                                     const float* __restrict__ bias,
                                                     unsigned int* __restrict__ out, int nv,
                                                     const float* __restrict__ Wn3,
                                                     unsigned int* __restrict__ zout) {
    constexpr int KTOT = 2 * KX;
    constexpr int KW = KTOT + 8;      // weight LDS row stride (bf16), bank-rotating
    constexpr int NT = COUT / 16;     // n-tiles per wave
    constexpr int MT = 2;             // m-tiles per wave (32 vertices)
    constexpr int SXU = KX / 2;       // x row stride in uints
    constexpr int KS = KX / 32;       // k-steps per source
    constexpr int VPB = 128;          // vertices per block
    constexpr int NCH = KX / 8;       // 16B chunks per gathered row
    constexpr int NBW = KX + 8;       // nb_s row stride (bf16 elems); keeps 16B align
    __shared__ __align__(16) unsigned short bt[COUT * KW];
    __shared__ __align__(16) unsigned short nb_s[VPB * NBW];
    __shared__ float wn3_s[192];

    // Stage weights: bt[c][kk], kk<KX -> Ws, else Wn.
    for (int i = threadIdx.x; i < COUT * KTOT; i += 256) {
        int c = i / KTOT;
        int kk = i - c * KTOT;
        int j = (kk < KX) ? kk : kk - KX;
        const float* W = (kk < KX) ? Ws : Wn;
        float w = 0.f;
        if (j < VALID_CIN) {
            int sr = REMAP0 ? ((j < 16) ? (j + 3) : (j - 16)) : j;
            w = W[sr * COUT + c];
        }
        bt[c * KW + kk] = bf16_1(w);
    }
    if constexpr (PREMUL) {
        if (threadIdx.x < 192) wn3_s[threadIdx.x] = Wn3[threadIdx.x];
    }

    // Gather phase: accumulate neighbor rows in registers, write bf16 to LDS.
    const int vb0 = blockIdx.x * VPB;
    for (int task = threadIdx.x; task < VPB * NCH; task += 256) {
        const int vloc = task / NCH;
        const int ch = task - vloc * NCH;
        const int v = vb0 + vloc;
        unsigned short* dst = nb_s + vloc * NBW + ch * 8;
        if (v < nv) {
            int beg = rowStart[v];
            int end = rowStart[v + 1];
            float a0 = 0.f, a1 = 0.f, a2 = 0.f, a3 = 0.f,
                  a4 = 0.f, a5 = 0.f, a6 = 0.f, a7 = 0.f;
            int j = beg;
            for (; j + 3 < end; j += 4) {
                int s0 = csrSrc[j];
                int s1 = csrSrc[j + 1];
                int s2 = csrSrc[j + 2];
                int s3 = csrSrc[j + 3];
                uint4 q0 = ((const uint4*)(x + (size_t)s0 * SXU))[ch];
                uint4 q1 = ((const uint4*)(x + (size_t)s1 * SXU))[ch];
                uint4 q2 = ((const uint4*)(x + (size_t)s2 * SXU))[ch];
                uint4 q3 = ((const uint4*)(x + (size_t)s3 * SXU))[ch];
                a0 += bf_lo(q0.x); a1 += bf_hi(q0.x);
                a2 += bf_lo(q0.y); a3 += bf_hi(q0.y);
                a4 += bf_lo(q0.z); a5 += bf_hi(q0.z);
                a6 += bf_lo(q0.w); a7 += bf_hi(q0.w);
                a0 += bf_lo(q1.x); a1 += bf_hi(q1.x);
                a2 += bf_lo(q1.y); a3 += bf_hi(q1.y);
                a4 += bf_lo(q1.z); a5 += bf_hi(q1.z);
                a6 += bf_lo(q1.w); a7 += bf_hi(q1.w);
                a0 += bf_lo(q2.x); a1 += bf_hi(q2.x);
                a2 += bf_lo(q2.y); a3 += bf_hi(q2.y);
                a4 += bf_lo(q2.z); a5 += bf_hi(q2.z);
                a6 += bf_lo(q2.w); a7 += bf_hi(q2.w);
                a0 += bf_lo(q3.x); a1 += bf_hi(q3.x);
                a2 += bf_lo(q3.y); a3 += bf_hi(q3.y);
                a4 += bf_lo(q3.z); a5 += bf_hi(q3.z);
                a6 += bf_lo(q3.w); a7 += bf_hi(q3.w);
            }
            for (; j < end; ++j) {
                int s = csrSrc[j];
                uint4 q = ((const uint4*)(x + (size_t)s * SXU))[ch];
                a0 += bf_lo(q.x); a1 += bf_hi(q.x);
                a2 += bf_lo(q.y); a3 += bf_hi(q.y);
                a4 += bf_lo(q.z); a5 += bf_hi(q.z);
                a6 += bf_lo(q.w); a7 += bf_hi(q.w);
            }
            const float id = invdeg[v];
            uint4 o;
            o.x = bf16_pack2(a0 * id, a1 * id); o.y = bf16_pack2(a2 * id, a3 * id);
            o.z = bf16_pack2(a4 * id, a5 * id); o.w = bf16_pack2(a6 * id, a7 * id);
            *(uint4*)dst = o;
        } else {
            *(uint4*)dst = make_uint4(0u, 0u, 0u, 0u);
        }
    }
    __syncthreads();

    const int lane = threadIdx.x & 63;
    const int wid = threadIdx.x >> 6;
    const int v0 = vb0 + wid * (MT * 16);
    const int row = lane & 15;
    const int kg = lane >> 4;         // k-subgroup: 8 contiguous k at kg*8

    f4_t acc[MT][NT] = {};

    #pragma unroll
    for (int ks = 0; ks < 2 * KS; ++ks) {
        bf8_t afrag[MT];
        if (ks < KS) {
            const int kbase = ks * 32;
            #pragma unroll
            for (int mt = 0; mt < MT; ++mt) {
                int v = v0 + mt * 16 + row;
                v = min(v, nv - 1);   // clamp: duplicate row, masked at store
                afrag[mt] = *(const bf8_t*)(x + (size_t)v * SXU + ((kbase + kg * 8) >> 1));
            }
        } else {
            const int kbase = (ks - KS) * 32;
            #pragma unroll
            for (int mt = 0; mt < MT; ++mt) {
                const int vloc = wid * (MT * 16) + mt * 16 + row;
                afrag[mt] = *(const bf8_t*)(nb_s + vloc * NBW + kbase + kg * 8);
            }
        }
        #pragma unroll
        for (int nt = 0; nt < NT; ++nt) {
            bf8_t bfrag = *(const bf8_t*)(bt + (nt * 16 + row) * KW + ks * 32 + kg * 8);
            #pragma unroll
            for (int mt = 0; mt < MT; ++mt)
                acc[mt][nt] = __builtin_amdgcn_mfma_f32_16x16x32_bf16(afrag[mt], bfrag,
                                                                      acc[mt][nt], 0, 0, 0);
        }
    }

    // Epilogue: bias + leaky relu, bf16 2B stores; optional fused premul.
    unsigned short* po = (unsigned short*)out;
    float bq[NT];
    #pragma unroll
    for (int nt = 0; nt < NT; ++nt) bq[nt] = bias[nt * 16 + row];
    #pragma unroll
    for (int mt = 0; mt < MT; ++mt) {
        #pragma unroll
        for (int r = 0; r < 4; ++r) {
            const int v = v0 + mt * 16 + kg * 4 + r;
            float tv[NT];
            #pragma unroll
            for (int nt = 0; nt < NT; ++nt) {
                float t = acc[mt][nt][r] + bq[nt];
                t = (t >= 0.f) ? t : SLOPE * t;
                tv[nt] = t;
                if (v < nv) po[(size_t)v * COUT + nt * 16 + row] = bf16_1(t);
            }
            if constexpr (PREMUL) {
                float z0 = 0.f, z1 = 0.f, z2 = 0.f;
                #pragma unroll
                for (int nt = 0; nt < NT; ++nt) {
                    const float* wr = wn3_s + (nt * 16 + row) * 3;
                    z0 += tv[nt] * wr[0];
                    z1 += tv[nt] * wr[1];
                    z2 += tv[nt] * wr[2];
                }
                #pragma unroll
                for (int m = 1; m < 16; m <<= 1) {
                    z0 += __shfl_xor(z0, m);
                    z1 += __shfl_xor(z1, m);
                    z2 += __shfl_xor(z2, m);
                }
                if (row == 0 && v < nv) {
                    uint2 o;
                    o.x = bf16_pack2(z0, z1);
                    o.y = bf16_pack2(z2, 0.f);
                    *(uint2*)(zout + (size_t)v * 2) = o;
                }
            }
        }
    }
}

// Final (fused z-gather): out = verts + SCALE*(h3@Ws3 + gather(z)*inv_deg + b3)
__global__ __launch_bounds__(256) void k_final(const unsigned int* __restrict__ h,
                                               const unsigned int* __restrict__ z,
                                               const int* __restrict__ rowStart,
                                               const int* __restrict__ csrSrc,
                                               const float* __restrict__ invdeg,
                                               const float* __restrict__ ws,
                                               const float* __restrict__ b,
                                               const float* __restrict__ verts,
                                               float* __restrict__ out, int nv) {
    __shared__ float w_s[64 * 3];
    if (threadIdx.x < 64 * 3) w_s[threadIdx.x] = ws[threadIdx.x];
    __syncthreads();
    int v = blockIdx.x * 256 + threadIdx.x;
    if (v >= nv) return;
    // neighbor gather of premultiplied z (800 KB, L2-resident), 4x unrolled
    float n0 = 0.f, n1 = 0.f, n2 = 0.f;
    {
        int beg = rowStart[v];
        int end = rowStart[v + 1];
        int j = beg;
        for (; j + 3 < end; j += 4) {
            int s0 = csrSrc[j];
            int s1 = csrSrc[j + 1];
            int s2 = csrSrc[j + 2];
            int s3 = csrSrc[j + 3];
            uint2 q0 = *(const uint2*)(z + (size_t)s0 * 2);
            uint2 q1 = *(const uint2*)(z + (size_t)s1 * 2);
            uint2 q2 = *(const uint2*)(z + (size_t)s2 * 2);
            uint2 q3 = *(const uint2*)(z + (size_t)s3 * 2);
            n0 += bf_lo(q0.x); n1 += bf_hi(q0.x); n2 += bf_lo(q0.y);
            n0 += bf_lo(q1.x); n1 += bf_hi(q1.x); n2 += bf_lo(q1.y);
            n0 += bf_lo(q2.x); n1 += bf_hi(q2.x); n2 += bf_lo(q2.y);
            n0 += bf_lo(q3.x); n1 += bf_hi(q3.x); n2 += bf_lo(q3.y);
        }
        for (; j < end; ++j) {
            int s = csrSrc[j];
            uint2 q = *(const uint2*)(z + (size_t)s * 2);
            n0 += bf_lo(q.x); n1 += bf_hi(q.x); n2 += bf_lo(q.y);
        }
    }
    const uint4* hr = (const uint4*)(h + (size_t)v * 32);
    float a0 = b[0], a1 = b[1], a2 = b[2];
    #pragma unroll
    for (int q = 0; q < 8; ++q) {
        uint4 hv = hr[q];
        float f[8] = {bf_lo(hv.x), bf_hi(hv.x), bf_lo(hv.y), bf_hi(hv.y),
                      bf_lo(hv.z), bf_hi(hv.z), bf_lo(hv.w), bf_hi(hv.w)};
        #pragma unroll
        for (int i = 0; i < 8; ++i) {
            int k = q * 8 + i;
            a0 += f[i] * w_s[k * 3 + 0];
            a1 += f[i] * w_s[k * 3 + 1];
            a2 += f[i] * w_s[k * 3 + 2];
        }
    }
    float id = invdeg[v];
    a0 += n0 * id; a1 += n1 * id; a2 += n2 * id;
    out[(size_t)v * 3 + 0] = verts[(size_t)v * 3 + 0] + SCALE * a0;
    out[(size_t)v * 3 + 1] = verts[(size_t)v * 3 + 1] + SCALE * a1;
    out[(size_t)v * 3 + 2] = verts[(size_t)v * 3 + 2] + SCALE * a2;
}

// ---------------------------------------------------------------------------
extern "C" void kernel_launch(void* const* d_in, const int* in_sizes, int n_in,
                              void* d_out, int out_size, void* d_ws, size_t ws_size,
                              hipStream_t stream) {
    const float* img   = (const float*)d_in[0];
    const float* verts = (const float*)d_in[1];
    const int*   esrc  = (const int*)d_in[2];
    const int*   edst  = (const int*)d_in[3];
    const float* ws0 = (const float*)d_in[4];
    const float* wn0 = (const float*)d_in[5];
    const float* b0  = (const float*)d_in[6];
    const float* ws1 = (const float*)d_in[7];
    const float* wn1 = (const float*)d_in[8];
    const float* b1  = (const float*)d_in[9];
    const float* ws2 = (const float*)d_in[10];
    const float* wn2 = (const float*)d_in[11];
    const float* b2  = (const float*)d_in[12];
    const float* ws3 = (const float*)d_in[13];
    const float* wn3 = (const float*)d_in[14];
    const float* b3  = (const float*)d_in[15];

    const int nv = in_sizes[1] / 3;
    const int ne = in_sizes[2];

    char* base = (char*)d_ws;
    size_t off = 0;
    auto alloc = [&](size_t bytes) -> void* {
        off = (off + 255) & ~(size_t)255;
        void* p = base + off;
        off += bytes;
        return p;
    };
    float* invdeg   = (float*)alloc((size_t)nv * 4);
    int*   rowStart = (int*)alloc((size_t)(nv + 1) * 4);
    int*   bucketCursor = (int*)alloc(256 * 4);
    int*   csrSrc   = (int*)alloc((size_t)ne * 4);
    unsigned int* pairs = (unsigned int*)alloc((size_t)256 * CAPB * 4);
    unsigned int* A   = (unsigned int*)alloc((size_t)nv * 32 * 4);  // feats(16u) then h2(32u)
    unsigned int* B   = (unsigned int*)alloc((size_t)nv * 32 * 4);  // h1(16u) then h3(32u)
    unsigned int* Z   = (unsigned int*)alloc((size_t)nv * 2 * 4);   // bf16 premultiplied
    unsigned int* timg = (unsigned int*)alloc((size_t)VOL * 16 * 2);

    auto blocks = [](long long n) { return (int)((n + 255) / 256); };
    const int nbuckets = (nv + 511) >> 9;
    const int lb = (nv + 127) / 128;  // fused layers: 128 vertices per block

    // zero the per-bucket cursors
    hipMemsetAsync(bucketCursor, 0, 256 * 4, stream);
    // streaming transpose (BW-bound form)
    k_transpose<<<VOL / 2 / 256, 256, 0, stream>>>(img, timg);
    // single-pass bucket (fixed regions) -> per-bucket sort (dense CSR)
    k_bucket<<<(ne + EPB - 1) / EPB, 256, 0, stream>>>(esrc, edst, bucketCursor,
                                                       pairs, rowStart, ne, nv);
    k_binsort<<<nbuckets, 256, 0, stream>>>(pairs, bucketCursor, rowStart, invdeg, csrSrc, nv);

    // Features (channel-last bf16 volume) -> bf16 feats
    k_sample<<<blocks((long long)nv * 2), 256, 0, stream>>>(timg, verts, A, nv);

    // Layer 0: 19 -> 32 (feats stride 16u, KX=32)
    k_layer_fused<32, 32, true, 19, false><<<lb, 256, 0, stream>>>(
        A, rowStart, csrSrc, invdeg, ws0, wn0, b0, B, nv, nullptr, nullptr);

    // Layer 1: 32 -> 64 (h1 stride 16u, KX=32)
    k_layer_fused<32, 64, false, 32, false><<<lb, 256, 0, stream>>>(
        B, rowStart, csrSrc, invdeg, ws1, wn1, b1, A, nv, nullptr, nullptr);

    // Layer 2: 64 -> 64 (h2 stride 32u, KX=64), fused premul z = h3 @ Wn3
    k_layer_fused<64, 64, false, 64, true><<<lb, 256, 0, stream>>>(
        A, rowStart, csrSrc, invdeg, ws2, wn2, b2, B, nv, wn3, Z);

    // Layer 3: fused gather+final update
    k_final<<<blocks(nv), 256, 0, stream>>>(
        B, Z, rowStart, csrSrc, invdeg, ws3, b3, verts, (float*)d_out, nv);
}